// Round 7
// baseline (419.762 us; speedup 1.0000x reference)
//
#include <hip/hip_runtime.h>

// LinearAttention forward on gfx950.
// R4: Wg1 folded into QKV GEMM (N=6272); silu+rotate fused into QKV epilogue
// via permuted q/k weight columns; gated RMSNorm fused into attn_out; 16-wide
// N-supertile swizzle in gemm_bt.
// R8: sigmoid fused into gate GEMM; factored score-decay exp; attn_out 2/CU.
// R10: rope LUT; v stored transposed into vT from QKV epilogue; merged prep.
// R11: v transposed store now staged through LDS (sV[64][136]) -> 16B-contig
// 256B-per-row stores into vT (R10's direct scatter was 8B x 4KB-stride =
// 16 cacheline touches/instr; cost QKV +20us). 8 dispatches.

#define DEV __device__ __forceinline__
typedef unsigned short u16;
typedef __bf16 bf16x8 __attribute__((ext_vector_type(8)));
typedef float f32x4 __attribute__((ext_vector_type(4)));
typedef u16 u16x8 __attribute__((ext_vector_type(8)));
typedef u16 u16x4 __attribute__((ext_vector_type(4)));

DEV u16 f2bf(float f) {
  unsigned u = __builtin_bit_cast(unsigned, f);
  u += 0x7fffu + ((u >> 16) & 1u);
  return (u16)(u >> 16);
}
DEV float bf2f(u16 h) {
  unsigned u = ((unsigned)h) << 16;
  return __builtin_bit_cast(float, u);
}
DEV void async16(const u16* g, u16* l) {
  __builtin_amdgcn_global_load_lds(
      (const __attribute__((address_space(1))) unsigned int*)g,
      (__attribute__((address_space(3))) unsigned int*)l, 16, 0, 0);
}

// ---------------- prep: x->bf16 | weight transposes | rope LUT ----------------
__global__ void prep_all(const float* __restrict__ x,
                         const float* __restrict__ Wq, const float* __restrict__ Wk,
                         const float* __restrict__ Wv, const float* __restrict__ Wo,
                         const float* __restrict__ Wg1, const float* __restrict__ Wg2,
                         u16* __restrict__ xb, u16* __restrict__ wtqkvg,
                         u16* __restrict__ wot, u16* __restrict__ wg2t,
                         float* __restrict__ rope) {
  int id = blockIdx.x;
  if (id < 8192) {
    long i = ((long)id * 256 + threadIdx.x) * 4;
    float4 v = *(const float4*)(x + i);
    ushort4 p;
    p.x = f2bf(v.x); p.y = f2bf(v.y); p.z = f2bf(v.z); p.w = f2bf(v.w);
    *(ushort4*)(xb + i) = p;
    return;
  }
  if (id >= 25088) {
    int idx = (id - 25088) * 256 + threadIdx.x;  // 131072 = 2048 t x 64 jj
    int t = idx >> 6, jj = idx & 63;
    float th = exp2f(-13.287712379549449f * (float)jj * (1.f / 64.f));
    float sn, cs;
    sincosf((float)t * th, &sn, &cs);
    ((float2*)rope)[idx] = make_float2(cs, sn);
    return;
  }
  id -= 8192;
  __shared__ float t[32][33];
  const float* in; u16* out; int K, N, bx, by;
  bool perm = false;
  if (id < 12288) {
    int w = id >> 12, tt = id & 4095;
    in = (w == 0) ? Wq : (w == 1) ? Wk : Wv;
    out = wtqkvg + (long)w * 2048 * 2048;
    K = 2048; N = 2048; bx = tt & 63; by = tt >> 6;
    perm = (w < 2);
  } else if (id < 16384) {
    int tt = id - 12288;
    in = Wo; out = wot; K = 2048; N = 2048; bx = tt & 63; by = tt >> 6;
  } else if (id < 16640) {
    int tt = id - 16384;
    in = Wg1; out = wtqkvg + 6144L * 2048; K = 2048; N = 128; bx = tt & 3; by = tt >> 2;
  } else {
    int tt = id - 16640;
    in = Wg2; out = wg2t; K = 128; N = 2048; bx = tt & 63; by = tt >> 6;
  }
  int c = threadIdx.x & 31, r0 = threadIdx.x >> 5;
  for (int r = r0; r < 32; r += 8)
    t[r][c] = in[(long)(by * 32 + r) * N + bx * 32 + c];
  __syncthreads();
  for (int r = r0; r < 32; r += 8) {
    int n = bx * 32 + r, nr = n;
    if (perm) {
      int h = n >> 7, j = n & 127, jj = j & 63, hi = j >> 6;
      nr = h * 128 + (jj & 15) + 32 * (jj >> 4) + 16 * hi;
    }
    out[(long)nr * K + by * 32 + c] = f2bf(t[c][r]);
  }
}

// ---------------- GEMM: C[M][N] = A[M][K] @ B^T, B stored [N][K], bf16 in ----------------
// rot=1: cols<4096 silu+LRPE-rotate (rope LUT); cols [4096,6144) v -> VT
//        transposed via sV LDS staging (coalesced 16B stores); >=6144 generic.
// rot=2: sigmoid applied in the bf16 store (gate pre-activation).
template <typename OutT>
__global__ __launch_bounds__(256, 2) void gemm_bt(
    const u16* __restrict__ A, const u16* __restrict__ B, OutT* __restrict__ C,
    int M, int N, int K, int lda, int ldb, int ldc, int rot,
    int nc, long sA1, long sA2, long sB1, long sB2, long sC1, long sC2,
    const float* __restrict__ rope, u16* __restrict__ VT) {
  __shared__ u16 sA[128 * 32], sB[128 * 32];
  __shared__ u16 sV[64 * 136];  // v-epilogue transpose staging (16B-aligned rows)
  {
    int z = blockIdx.z, z1 = z / nc, z2 = z % nc;
    A += z1 * sA1 + z2 * sA2;
    B += z1 * sB1 + z2 * sB2;
    C += z1 * sC1 + z2 * sC2;
  }
  int bxs, bys;
  {
    int lin = blockIdx.x + gridDim.x * blockIdx.y;
    int per = 16 * gridDim.y;
    int g = lin / per, r = lin % per;
    int base = g * 16;
    int w = min(16, (int)gridDim.x - base);
    bxs = base + r % w; bys = r / w;
  }
  const int tid = threadIdx.x, lane = tid & 63, wid = tid >> 6;
  const int bm = bys * 128, bn = bxs * 128;
  const int ch0 = wid * 2, ch1 = ch0 + 1;
  const int lr = lane >> 2;                                  // local row 0..15
  const int ak = (((lane & 3) - ((lane >> 3) & 3)) & 3) * 8; // rotated k-piece
  const int ar0 = ch0 * 16 + lr, ar1 = ch1 * 16 + lr;
  const u16* gA0 = A + (long)(bm + ar0) * lda + ak;
  const u16* gA1 = A + (long)(bm + ar1) * lda + ak;
  const u16* gB0 = B + (long)(bn + ar0) * ldb + ak;
  const u16* gB1 = B + (long)(bn + ar1) * ldb + ak;
  u16* lA0 = sA + ch0 * 512; u16* lA1 = sA + ch1 * 512;
  u16* lB0 = sB + ch0 * 512; u16* lB1 = sB + ch1 * 512;
  const int wm = (wid & 1) * 64, wn = (wid >> 1) * 64;
  const int fm = lane & 15, kq = lane >> 4;
  const int qs = ((kq + (fm >> 1)) & 3) * 8;
  const int aoff = (wm >> 4) * 512 + fm * 32 + qs;
  const int boff = (wn >> 4) * 512 + fm * 32 + qs;
  f32x4 acc[4][4] = {};
  for (int kb = 0; kb < K; kb += 32) {
    async16(gA0, lA0); async16(gA1, lA1);
    async16(gB0, lB0); async16(gB1, lB1);
    gA0 += 32; gA1 += 32; gB0 += 32; gB1 += 32;
    __syncthreads();
    bf16x8 af[4], bfr[4];
#pragma unroll
    for (int i = 0; i < 4; i++) af[i] = *(const bf16x8*)&sA[aoff + i * 512];
#pragma unroll
    for (int i = 0; i < 4; i++) bfr[i] = *(const bf16x8*)&sB[boff + i * 512];
#pragma unroll
    for (int mt = 0; mt < 4; mt++)
#pragma unroll
      for (int nt = 0; nt < 4; nt++)
        acc[mt][nt] = __builtin_amdgcn_mfma_f32_16x16x32_bf16(af[mt], bfr[nt], acc[mt][nt], 0, 0, 0);
    __syncthreads();
  }
  const int cr = (lane >> 4) * 4;
  if constexpr (sizeof(OutT) == 2) {
    if (rot == 1 && bn < 4096) {
      // silu + rotate epilogue via rope LUT; lane holds permuted cols.
#pragma unroll
      for (int mt = 0; mt < 4; mt++)
#pragma unroll
        for (int r = 0; r < 4; r++) {
          long row = bm + wm + mt * 16 + cr + r;
          const float2* rp = (const float2*)rope + (long)(row & 2047) * 64;
#pragma unroll
          for (int np = 0; np < 4; np += 2) {
            float x1 = acc[mt][np][r], x2 = acc[mt][np + 1][r];
            x1 = x1 / (1.f + __expf(-x1));
            x2 = x2 / (1.f + __expf(-x2));
            int jj = fm + 16 * ((wn >> 5) + (np >> 1));
            float2 cn = rp[jj];
            C[row * ldc + bn + jj]      = f2bf(x1 * cn.x - x2 * cn.y);
            C[row * ldc + bn + 64 + jj] = f2bf(x1 * cn.y + x2 * cn.x);
          }
        }
      return;
    }
    if (rot == 1 && bn < 6144) {
      // v block: tile is 128t x 128d of one (b,h). Transpose via sV per d-half:
      // owning waves write u16x4 (4 consecutive t), all threads store 16B-contig.
      const int bq = bm >> 11;
      const int head = (bn - 4096) >> 7;
      const int tb = bm & 2047;
      u16* vbase = VT + (long)(bq * 16 + head) * 128 * 2048 + tb;
#pragma unroll
      for (int dh = 0; dh < 2; dh++) {
        if ((wid >> 1) == dh) {
#pragma unroll
          for (int mt = 0; mt < 4; mt++)
#pragma unroll
            for (int nt = 0; nt < 4; nt++) {
              int dl = nt * 16 + fm;
              int t0 = wm + mt * 16 + cr;
              u16x4 pk;
#pragma unroll
              for (int r = 0; r < 4; r++) pk[r] = f2bf(acc[mt][nt][r]);
              *(u16x4*)&sV[dl * 136 + t0] = pk;
            }
        }
        __syncthreads();
#pragma unroll
        for (int it = 0; it < 4; it++) {
          int dl = it * 16 + (tid >> 4);
          int tc = (tid & 15) * 8;
          u16x8 vv = *(const u16x8*)&sV[dl * 136 + tc];
          *(u16x8*)(vbase + (long)(dh * 64 + dl) * 2048 + tc) = vv;
        }
        __syncthreads();
      }
      return;
    }
  }
#pragma unroll
  for (int mt = 0; mt < 4; mt++)
#pragma unroll
    for (int nt = 0; nt < 4; nt++)
#pragma unroll
      for (int r = 0; r < 4; r++) {
        long row = bm + wm + mt * 16 + cr + r;
        long col = bn + wn + nt * 16 + fm;
        float v = acc[mt][nt][r];
        if constexpr (sizeof(OutT) == 2) {
          if (rot == 2) v = 1.f / (1.f + __expf(-v));  // fused sigmoid (gate)
          C[row * ldc + col] = f2bf(v);
        } else {
          C[row * ldc + col] = v;
        }
      }
}

// ---------------- per-(b,h) k transpose: [n][dd] -> [dd][n] with decay fold ----------------
__global__ void transpose_k(const u16* __restrict__ qkv, u16* __restrict__ kdT) {
  __shared__ float t[32][33];
  int bh = blockIdx.z;
  int b = bh >> 4, h = bh & 15;
  int n0 = blockIdx.x * 32, d0 = blockIdx.y * 32;
  int cc = threadIdx.x & 31, rr0 = threadIdx.x >> 5;
  float log_lam = -exp2f(-0.5f * (float)(h + 1));
  for (int rr = rr0; rr < 32; rr += 8) {
    int n = n0 + rr;
    float v = bf2f(qkv[(long)(b * 2048 + n) * 6272 + 2048 + h * 128 + d0 + cc]);
    v *= expf(log_lam * (float)(127 - (n & 127)));
    t[rr][cc] = v;
  }
  __syncthreads();
  for (int rr = rr0; rr < 32; rr += 8)
    kdT[((long)bh * 128 + d0 + rr) * 2048 + n0 + cc] = f2bf(t[cc][rr]);
}

// ---------------- decay scan over chunks: S_c = lamC*S_{c-1} + U_{c-1}, S_0 = 0 ----------------
__global__ void scan_state(const u16* __restrict__ U, u16* __restrict__ S_all) {
  int blk = blockIdx.x; // 256 blocks: [bh:32][slice:8]
  int bh = blk >> 3, sl = blk & 7, h = bh & 15;
  float log_lam = -exp2f(-0.5f * (float)(h + 1));
  float lamC = expf(log_lam * 128.f);
  long off = (long)bh * 16 * 16384 + sl * 2048 + threadIdx.x * 8;
  float s[8];
#pragma unroll
  for (int j = 0; j < 8; j++) s[j] = 0.f;
  for (int c = 0; c < 16; c++) {
    long idx = off + (long)c * 16384;
    u16x8 sb;
#pragma unroll
    for (int j = 0; j < 8; j++) sb[j] = f2bf(s[j]);
    *(u16x8*)(S_all + idx) = sb;
    u16x8 ub = *(const u16x8*)(U + idx);
#pragma unroll
    for (int j = 0; j < 8; j++) s[j] = lamC * s[j] + bf2f(ub[j]);
  }
}

// ---------------- fused per-(b,h,c) attention output + gated RMSNorm ----------------
// gate input is PRE-SIGMOIDED (fused into gate GEMM epilogue, rot=2).
__global__ __launch_bounds__(256, 2) void attn_out(
    const u16* __restrict__ qkv, const u16* __restrict__ vT,
    const u16* __restrict__ S_all, const u16* __restrict__ gate,
    const float* __restrict__ nw, u16* __restrict__ nrm) {
  __shared__ u16 sA[128 * 32], sB[128 * 32], sK[128 * 32];
  __shared__ u16 sS[128 * 136]; // stride 136: breaks 16-way bank conflict
  __shared__ float sNorm[2][128];
  const int blk = blockIdx.x;
  const int bh = blk >> 4, c = blk & 15;
  const int b = bh >> 4, h = bh & 15;
  const float log_lam = -exp2f(-0.5f * (float)(h + 1));
  const int tid = threadIdx.x, lane = tid & 63, wid = tid >> 6;
  const int wm = (wid & 1) * 64, wn = (wid >> 1) * 64;
  const int fm = lane & 15, fq = lane >> 4, kq = lane >> 4;
  const int lr = lane >> 2;
  const int ak = (((lane & 3) - ((lane >> 3) & 3)) & 3) * 8;
  const int ch0 = wid * 2, ch1 = ch0 + 1;
  const int r0 = ch0 * 16 + lr, r1 = ch1 * 16 + lr;
  const int qs = ((kq + (fm >> 1)) & 3) * 8;
  const int aoff = (wm >> 4) * 512 + fm * 32 + qs;
  const int boff = (wn >> 4) * 512 + fm * 32 + qs;
  const u16* qbase = qkv + (long)(b * 2048 + c * 128) * 6272 + h * 128; // rows t, stride 6272
  const u16* kbase = qbase + 2048;                                     // rows s
  const u16* Sbase = S_all + ((long)bh * 16 + c) * 16384;              // [e][d], stride 128
  const u16* vbase = vT + (long)bh * 262144 + (long)c * 128;           // rows e, stride 2048

  f32x4 acc[4][4] = {}; // o_inter, then O total
  f32x4 sc[4][4] = {};  // scores
  // Phase 1+2: o_inter = Q @ S_c   and   scores = Q @ K^T (shared Q staging)
  for (int kb = 0; kb < 128; kb += 32) {
    async16(qbase + (long)r0 * 6272 + kb + ak, sA + ch0 * 512);
    async16(qbase + (long)r1 * 6272 + kb + ak, sA + ch1 * 512);
    async16(Sbase + r0 * 128 + kb + ak, sB + ch0 * 512);
    async16(Sbase + r1 * 128 + kb + ak, sB + ch1 * 512);
    async16(kbase + (long)r0 * 6272 + kb + ak, sK + ch0 * 512);
    async16(kbase + (long)r1 * 6272 + kb + ak, sK + ch1 * 512);
    __syncthreads();
    bf16x8 aq[4], bs[4], bk[4];
#pragma unroll
    for (int i = 0; i < 4; i++) {
      aq[i] = *(const bf16x8*)&sA[aoff + i * 512];
      bs[i] = *(const bf16x8*)&sB[boff + i * 512];
      bk[i] = *(const bf16x8*)&sK[boff + i * 512];
    }
#pragma unroll
    for (int mt = 0; mt < 4; mt++)
#pragma unroll
      for (int nt = 0; nt < 4; nt++) {
        acc[mt][nt] = __builtin_amdgcn_mfma_f32_16x16x32_bf16(aq[mt], bs[nt], acc[mt][nt], 0, 0, 0);
        sc[mt][nt] = __builtin_amdgcn_mfma_f32_16x16x32_bf16(aq[mt], bk[nt], sc[mt][nt], 0, 0, 0);
      }
    __syncthreads();
  }
  // scale o_inter rows by decay_q(t) = exp(log_lam*(t+1))
#pragma unroll
  for (int mt = 0; mt < 4; mt++)
#pragma unroll
    for (int r = 0; r < 4; r++) {
      int t = wm + mt * 16 + fq * 4 + r;
      float d = __expf(log_lam * (float)(t + 1));
#pragma unroll
      for (int nt = 0; nt < 4; nt++) acc[mt][nt][r] *= d;
    }
  // mask+decay scores, write bf16 to sS[t][s].
  // e^{lam*(t-s)} factored: eT(t)*eS(s); both finite on all SELECTED lanes
  // (worst valid pair e^{+44.5} * e^{-44.5}; masked lanes may see inf,
  // discarded by the select).
  float eS[4];
#pragma unroll
  for (int nt = 0; nt < 4; nt++)
    eS[nt] = __expf(log_lam * (float)(63 - (nt * 16 + fm)));
#pragma unroll
  for (int mt = 0; mt < 4; mt++)
#pragma unroll
    for (int r = 0; r < 4; r++) {
      int t = wm + mt * 16 + fq * 4 + r;
      float eT = __expf(log_lam * (float)(t - wn - 63));
#pragma unroll
      for (int nt = 0; nt < 4; nt++) {
        int s = wn + nt * 16 + fm;
        float v = sc[mt][nt][r];
        v = (t >= s) ? v * (eT * eS[nt]) : 0.f;
        sS[t * 136 + s] = f2bf(v);
      }
    }
  __syncthreads();
  // Phase 3: O += scores @ V   (A from sS, B staged from vT)
  for (int kb = 0; kb < 128; kb += 32) {
    async16(vbase + r0 * 2048 + kb + ak, sB + ch0 * 512);
    async16(vbase + r1 * 2048 + kb + ak, sB + ch1 * 512);
    __syncthreads();
    bf16x8 as[4], bv[4];
#pragma unroll
    for (int i = 0; i < 4; i++) {
      as[i] = *(const bf16x8*)&sS[(wm + i * 16 + fm) * 136 + kb + kq * 8];
      bv[i] = *(const bf16x8*)&sB[boff + i * 512];
    }
#pragma unroll
    for (int mt = 0; mt < 4; mt++)
#pragma unroll
      for (int nt = 0; nt < 4; nt++)
        acc[mt][nt] = __builtin_amdgcn_mfma_f32_16x16x32_bf16(as[mt], bv[nt], acc[mt][nt], 0, 0, 0);
    __syncthreads();
  }
  // ---- fused gated group-RMSNorm: x = O*gate (gate pre-sigmoided) ----
  const u16* gbase = gate + (long)(b * 2048 + c * 128) * 2048 + h * 128;
  float nwv[4];
#pragma unroll
  for (int nt = 0; nt < 4; nt++) nwv[nt] = nw[h * 128 + wn + nt * 16 + fm];
  float part[4][4];
#pragma unroll
  for (int mt = 0; mt < 4; mt++)
#pragma unroll
    for (int r = 0; r < 4; r++) {
      int t = wm + mt * 16 + fq * 4 + r;
      float p = 0.f;
#pragma unroll
      for (int nt = 0; nt < 4; nt++) {
        int e = wn + nt * 16 + fm;
        float g = bf2f(gbase[(long)t * 2048 + e]);
        float x = acc[mt][nt][r] * g;
        acc[mt][nt][r] = x;
        p += x * x;
      }
      part[mt][r] = p;
    }
#pragma unroll
  for (int o = 1; o < 16; o <<= 1)
#pragma unroll
    for (int mt = 0; mt < 4; mt++)
#pragma unroll
      for (int r = 0; r < 4; r++) part[mt][r] += __shfl_xor(part[mt][r], o);
  if (fm == 0) {
#pragma unroll
    for (int mt = 0; mt < 4; mt++)
#pragma unroll
      for (int r = 0; r < 4; r++)
        sNorm[wid >> 1][wm + mt * 16 + fq * 4 + r] = part[mt][r];
  }
  __syncthreads();
  long orow0 = (long)(b * 2048 + c * 128);
#pragma unroll
  for (int mt = 0; mt < 4; mt++)
#pragma unroll
    for (int r = 0; r < 4; r++) {
      int t = wm + mt * 16 + fq * 4 + r;
      float ms = (sNorm[0][t] + sNorm[1][t]) * (1.f / 128.f);
      float rs = rsqrtf(ms + 1e-6f);
#pragma unroll
      for (int nt = 0; nt < 4; nt++) {
        int e = wn + nt * 16 + fm;
        nrm[(orow0 + t) * 2048 + h * 128 + e] = f2bf(acc[mt][nt][r] * rs * nwv[nt]);
      }
    }
}

// ---------------- host ----------------
extern "C" void kernel_launch(void* const* d_in, const int* in_sizes, int n_in,
                              void* d_out, int out_size, void* d_ws, size_t ws_size,
                              hipStream_t stream) {
  (void)in_sizes; (void)n_in; (void)out_size; (void)ws_size;
  const float* x   = (const float*)d_in[0];
  const float* Wq  = (const float*)d_in[1];
  const float* Wk  = (const float*)d_in[2];
  const float* Wv  = (const float*)d_in[3];
  const float* Wo  = (const float*)d_in[4];
  const float* Wg1 = (const float*)d_in[5];
  const float* Wg2 = (const float*)d_in[6];
  const float* nw  = (const float*)d_in[7];
  float* out = (float*)d_out;

  char* ws = (char*)d_ws;
  size_t off = 0;
  auto alloc = [&](size_t bytes) -> void* {
    void* p = ws + off;
    off += (bytes + 255) & ~(size_t)255;
    return p;
  };
  u16* xb    = (u16*)alloc(4096UL * 2048 * 2);
  u16* wtqkv = (u16*)alloc(6272UL * 2048 * 2); // [Wq^T perm | Wk^T perm | Wv^T | Wg1^T]
  u16* wot   = (u16*)alloc(2048UL * 2048 * 2);
  u16* wg2t  = (u16*)alloc(2048UL * 128 * 2);
  u16* qkvg  = (u16*)alloc(4096UL * 6272 * 2); // q(rot) | k(rot) | (v unused) | g1
  u16* gate  = (u16*)alloc(4096UL * 2048 * 2);
  u16* kdT   = (u16*)alloc(32UL * 128 * 2048 * 2);
  u16* vT    = (u16*)alloc(32UL * 128 * 2048 * 2);
  u16* Ubuf  = (u16*)alloc(512UL * 16384 * 2);
  u16* S_all = (u16*)alloc(512UL * 16384 * 2);
  u16* nrm   = (u16*)alloc(4096UL * 2048 * 2);
  float* rope = (float*)alloc(2048UL * 64 * 8); // float2 [t][jj]

  // 1. prep: x conversion, weight transposes, rope LUT (one launch)
  prep_all<<<dim3(25600), dim3(256), 0, stream>>>(x, Wq, Wk, Wv, Wo, Wg1, Wg2,
                                                  xb, wtqkv, wot, wg2t, rope);
  // 2. QKV+g1 projection: silu+rotate (LUT) on q,k; v stored transposed to vT
  gemm_bt<u16><<<dim3(49, 32, 1), dim3(256), 0, stream>>>(xb, wtqkv, qkvg,
      4096, 6272, 2048, 2048, 2048, 6272, 1, 1, 0, 0, 0, 0, 0, 0, rope, vT);
  // gate = sigmoid(g1 @ Wg2^T)  (sigmoid fused, rot=2)
  gemm_bt<u16><<<dim3(16, 32, 1), dim3(256), 0, stream>>>(qkvg + 6144, wg2t, gate,
      4096, 2048, 128, 6272, 128, 2048, 2, 1, 0, 0, 0, 0, 0, 0, nullptr, nullptr);
  // 3. attention
  transpose_k<<<dim3(64, 4, 32), dim3(256), 0, stream>>>(qkvg, kdT);
  gemm_bt<u16><<<dim3(1, 1, 512), dim3(256), 0, stream>>>(vT, kdT, Ubuf,
      128, 128, 128, 2048, 2048, 128, 0,
      16, 262144L, 128L, 262144L, 128L, 262144L, 16384L, nullptr, nullptr);
  scan_state<<<dim3(256), dim3(256), 0, stream>>>(Ubuf, S_all);
  attn_out<<<dim3(512), dim3(256), 0, stream>>>(qkvg, vT, S_all, gate, nw, nrm);
  // 4. output projection
  gemm_bt<float><<<dim3(16, 32, 1), dim3(256), 0, stream>>>(nrm, wot, out,
      4096, 2048, 2048, 2048, 2048, 2048, 0, 1, 0, 0, 0, 0, 0, 0, nullptr, nullptr);
}

// Round 8
// 398.575 us; speedup vs baseline: 1.0532x; 1.0532x over previous
//
#include <hip/hip_runtime.h>

// LinearAttention forward on gfx950.
// R4: Wg1 folded into QKV GEMM (N=6272); silu+rotate fused into QKV epilogue
// via permuted q/k weight columns; gated RMSNorm fused into attn_out; 16-wide
// N-supertile swizzle in gemm_bt.
// R8: sigmoid fused into gate GEMM; factored score-decay exp; attn_out 2/CU.
// R10: rope LUT; v stored transposed into vT from QKV epilogue; merged prep.
// R12: fix R10/R11 regression = register-cliff (VGPR 56->80, +64 AGPR acc
// crossed 128-combined -> 3 waves/SIMD). gemm_bt now __launch_bounds__(256,4)
// (forces combined<=128); sV overlays sA/sB (dead after K-loop) via one 16KB
// smem block with XOR-swizzled [64][128] layout (LDS back to 16KB everywhere,
// ~2-way max bank aliasing). 8 dispatches.

#define DEV __device__ __forceinline__
typedef unsigned short u16;
typedef __bf16 bf16x8 __attribute__((ext_vector_type(8)));
typedef float f32x4 __attribute__((ext_vector_type(4)));
typedef u16 u16x8 __attribute__((ext_vector_type(8)));
typedef u16 u16x4 __attribute__((ext_vector_type(4)));

DEV u16 f2bf(float f) {
  unsigned u = __builtin_bit_cast(unsigned, f);
  u += 0x7fffu + ((u >> 16) & 1u);
  return (u16)(u >> 16);
}
DEV float bf2f(u16 h) {
  unsigned u = ((unsigned)h) << 16;
  return __builtin_bit_cast(float, u);
}
DEV void async16(const u16* g, u16* l) {
  __builtin_amdgcn_global_load_lds(
      (const __attribute__((address_space(1))) unsigned int*)g,
      (__attribute__((address_space(3))) unsigned int*)l, 16, 0, 0);
}

// ---------------- prep: x->bf16 | weight transposes | rope LUT ----------------
__global__ void prep_all(const float* __restrict__ x,
                         const float* __restrict__ Wq, const float* __restrict__ Wk,
                         const float* __restrict__ Wv, const float* __restrict__ Wo,
                         const float* __restrict__ Wg1, const float* __restrict__ Wg2,
                         u16* __restrict__ xb, u16* __restrict__ wtqkvg,
                         u16* __restrict__ wot, u16* __restrict__ wg2t,
                         float* __restrict__ rope) {
  int id = blockIdx.x;
  if (id < 8192) {
    long i = ((long)id * 256 + threadIdx.x) * 4;
    float4 v = *(const float4*)(x + i);
    ushort4 p;
    p.x = f2bf(v.x); p.y = f2bf(v.y); p.z = f2bf(v.z); p.w = f2bf(v.w);
    *(ushort4*)(xb + i) = p;
    return;
  }
  if (id >= 25088) {
    int idx = (id - 25088) * 256 + threadIdx.x;  // 131072 = 2048 t x 64 jj
    int t = idx >> 6, jj = idx & 63;
    float th = exp2f(-13.287712379549449f * (float)jj * (1.f / 64.f));
    float sn, cs;
    sincosf((float)t * th, &sn, &cs);
    ((float2*)rope)[idx] = make_float2(cs, sn);
    return;
  }
  id -= 8192;
  __shared__ float t[32][33];
  const float* in; u16* out; int K, N, bx, by;
  bool perm = false;
  if (id < 12288) {
    int w = id >> 12, tt = id & 4095;
    in = (w == 0) ? Wq : (w == 1) ? Wk : Wv;
    out = wtqkvg + (long)w * 2048 * 2048;
    K = 2048; N = 2048; bx = tt & 63; by = tt >> 6;
    perm = (w < 2);
  } else if (id < 16384) {
    int tt = id - 12288;
    in = Wo; out = wot; K = 2048; N = 2048; bx = tt & 63; by = tt >> 6;
  } else if (id < 16640) {
    int tt = id - 16384;
    in = Wg1; out = wtqkvg + 6144L * 2048; K = 2048; N = 128; bx = tt & 3; by = tt >> 2;
  } else {
    int tt = id - 16640;
    in = Wg2; out = wg2t; K = 128; N = 2048; bx = tt & 63; by = tt >> 6;
  }
  int c = threadIdx.x & 31, r0 = threadIdx.x >> 5;
  for (int r = r0; r < 32; r += 8)
    t[r][c] = in[(long)(by * 32 + r) * N + bx * 32 + c];
  __syncthreads();
  for (int r = r0; r < 32; r += 8) {
    int n = bx * 32 + r, nr = n;
    if (perm) {
      int h = n >> 7, j = n & 127, jj = j & 63, hi = j >> 6;
      nr = h * 128 + (jj & 15) + 32 * (jj >> 4) + 16 * hi;
    }
    out[(long)nr * K + by * 32 + c] = f2bf(t[c][r]);
  }
}

// ---------------- GEMM: C[M][N] = A[M][K] @ B^T, B stored [N][K], bf16 in ----------------
// rot=1: cols<4096 silu+LRPE-rotate (rope LUT); cols [4096,6144) v -> VT
//        transposed via sV overlay on sA/sB (XOR-swizzled, coalesced stores);
//        >=6144 generic. rot=2: sigmoid fused in the bf16 store.
template <typename OutT>
__global__ __launch_bounds__(256, 4) void gemm_bt(
    const u16* __restrict__ A, const u16* __restrict__ B, OutT* __restrict__ C,
    int M, int N, int K, int lda, int ldb, int ldc, int rot,
    int nc, long sA1, long sA2, long sB1, long sB2, long sC1, long sC2,
    const float* __restrict__ rope, u16* __restrict__ VT) {
  __shared__ u16 smem[8192];  // sA[0:4096] | sB[4096:8192]; reused as sV[64][128]
  u16* const sA = smem;
  u16* const sB = smem + 4096;
  {
    int z = blockIdx.z, z1 = z / nc, z2 = z % nc;
    A += z1 * sA1 + z2 * sA2;
    B += z1 * sB1 + z2 * sB2;
    C += z1 * sC1 + z2 * sC2;
  }
  int bxs, bys;
  {
    int lin = blockIdx.x + gridDim.x * blockIdx.y;
    int per = 16 * gridDim.y;
    int g = lin / per, r = lin % per;
    int base = g * 16;
    int w = min(16, (int)gridDim.x - base);
    bxs = base + r % w; bys = r / w;
  }
  const int tid = threadIdx.x, lane = tid & 63, wid = tid >> 6;
  const int bm = bys * 128, bn = bxs * 128;
  const int ch0 = wid * 2, ch1 = ch0 + 1;
  const int lr = lane >> 2;                                  // local row 0..15
  const int ak = (((lane & 3) - ((lane >> 3) & 3)) & 3) * 8; // rotated k-piece
  const int ar0 = ch0 * 16 + lr, ar1 = ch1 * 16 + lr;
  const u16* gA0 = A + (long)(bm + ar0) * lda + ak;
  const u16* gA1 = A + (long)(bm + ar1) * lda + ak;
  const u16* gB0 = B + (long)(bn + ar0) * ldb + ak;
  const u16* gB1 = B + (long)(bn + ar1) * ldb + ak;
  u16* lA0 = sA + ch0 * 512; u16* lA1 = sA + ch1 * 512;
  u16* lB0 = sB + ch0 * 512; u16* lB1 = sB + ch1 * 512;
  const int wm = (wid & 1) * 64, wn = (wid >> 1) * 64;
  const int fm = lane & 15, kq = lane >> 4;
  const int qs = ((kq + (fm >> 1)) & 3) * 8;
  const int aoff = (wm >> 4) * 512 + fm * 32 + qs;
  const int boff = (wn >> 4) * 512 + fm * 32 + qs;
  f32x4 acc[4][4] = {};
  for (int kb = 0; kb < K; kb += 32) {
    async16(gA0, lA0); async16(gA1, lA1);
    async16(gB0, lB0); async16(gB1, lB1);
    gA0 += 32; gA1 += 32; gB0 += 32; gB1 += 32;
    __syncthreads();
    bf16x8 af[4], bfr[4];
#pragma unroll
    for (int i = 0; i < 4; i++) af[i] = *(const bf16x8*)&sA[aoff + i * 512];
#pragma unroll
    for (int i = 0; i < 4; i++) bfr[i] = *(const bf16x8*)&sB[boff + i * 512];
#pragma unroll
    for (int mt = 0; mt < 4; mt++)
#pragma unroll
      for (int nt = 0; nt < 4; nt++)
        acc[mt][nt] = __builtin_amdgcn_mfma_f32_16x16x32_bf16(af[mt], bfr[nt], acc[mt][nt], 0, 0, 0);
    __syncthreads();
  }
  const int cr = (lane >> 4) * 4;
  if constexpr (sizeof(OutT) == 2) {
    if (rot == 1 && bn < 4096) {
      // silu + rotate epilogue via rope LUT; lane holds permuted cols.
#pragma unroll
      for (int mt = 0; mt < 4; mt++)
#pragma unroll
        for (int r = 0; r < 4; r++) {
          long row = bm + wm + mt * 16 + cr + r;
          const float2* rp = (const float2*)rope + (long)(row & 2047) * 64;
#pragma unroll
          for (int np = 0; np < 4; np += 2) {
            float x1 = acc[mt][np][r], x2 = acc[mt][np + 1][r];
            x1 = x1 / (1.f + __expf(-x1));
            x2 = x2 / (1.f + __expf(-x2));
            int jj = fm + 16 * ((wn >> 5) + (np >> 1));
            float2 cn = rp[jj];
            C[row * ldc + bn + jj]      = f2bf(x1 * cn.x - x2 * cn.y);
            C[row * ldc + bn + 64 + jj] = f2bf(x1 * cn.y + x2 * cn.x);
          }
        }
      return;
    }
    if (rot == 1 && bn < 6144) {
      // v block: 128t x 128d of one (b,h). Transpose via sV (= smem overlay,
      // XOR-swizzled [64][128]) per d-half; stores 16B-contig into vT.
      const int bq = bm >> 11;
      const int head = (bn - 4096) >> 7;
      const int tb = bm & 2047;
      u16* vbase = VT + (long)(bq * 16 + head) * 128 * 2048 + tb;
      u16* const sV = smem;
#pragma unroll
      for (int dh = 0; dh < 2; dh++) {
        __syncthreads();
        if ((wid >> 1) == dh) {
#pragma unroll
          for (int mt = 0; mt < 4; mt++)
#pragma unroll
            for (int nt = 0; nt < 4; nt++) {
              int dl = nt * 16 + fm;
              int t0 = wm + mt * 16 + cr;
              u16x4 pk;
#pragma unroll
              for (int r = 0; r < 4; r++) pk[r] = f2bf(acc[mt][nt][r]);
              *(u16x4*)&sV[dl * 128 + (t0 ^ ((fm & 15) << 3))] = pk;
            }
        }
        __syncthreads();
#pragma unroll
        for (int it = 0; it < 4; it++) {
          int dl = it * 16 + (tid >> 4);
          int tc = (tid & 15) * 8;
          u16x8 vv = *(const u16x8*)&sV[dl * 128 + (tc ^ ((dl & 15) << 3))];
          *(u16x8*)(vbase + (long)(dh * 64 + dl) * 2048 + tc) = vv;
        }
      }
      return;
    }
  }
#pragma unroll
  for (int mt = 0; mt < 4; mt++)
#pragma unroll
    for (int nt = 0; nt < 4; nt++)
#pragma unroll
      for (int r = 0; r < 4; r++) {
        long row = bm + wm + mt * 16 + cr + r;
        long col = bn + wn + nt * 16 + fm;
        float v = acc[mt][nt][r];
        if constexpr (sizeof(OutT) == 2) {
          if (rot == 2) v = 1.f / (1.f + __expf(-v));  // fused sigmoid (gate)
          C[row * ldc + col] = f2bf(v);
        } else {
          C[row * ldc + col] = v;
        }
      }
}

// ---------------- per-(b,h) k transpose: [n][dd] -> [dd][n] with decay fold ----------------
__global__ void transpose_k(const u16* __restrict__ qkv, u16* __restrict__ kdT) {
  __shared__ float t[32][33];
  int bh = blockIdx.z;
  int b = bh >> 4, h = bh & 15;
  int n0 = blockIdx.x * 32, d0 = blockIdx.y * 32;
  int cc = threadIdx.x & 31, rr0 = threadIdx.x >> 5;
  float log_lam = -exp2f(-0.5f * (float)(h + 1));
  for (int rr = rr0; rr < 32; rr += 8) {
    int n = n0 + rr;
    float v = bf2f(qkv[(long)(b * 2048 + n) * 6272 + 2048 + h * 128 + d0 + cc]);
    v *= expf(log_lam * (float)(127 - (n & 127)));
    t[rr][cc] = v;
  }
  __syncthreads();
  for (int rr = rr0; rr < 32; rr += 8)
    kdT[((long)bh * 128 + d0 + rr) * 2048 + n0 + cc] = f2bf(t[cc][rr]);
}

// ---------------- decay scan over chunks: S_c = lamC*S_{c-1} + U_{c-1}, S_0 = 0 ----------------
__global__ void scan_state(const u16* __restrict__ U, u16* __restrict__ S_all) {
  int blk = blockIdx.x; // 256 blocks: [bh:32][slice:8]
  int bh = blk >> 3, sl = blk & 7, h = bh & 15;
  float log_lam = -exp2f(-0.5f * (float)(h + 1));
  float lamC = expf(log_lam * 128.f);
  long off = (long)bh * 16 * 16384 + sl * 2048 + threadIdx.x * 8;
  float s[8];
#pragma unroll
  for (int j = 0; j < 8; j++) s[j] = 0.f;
  for (int c = 0; c < 16; c++) {
    long idx = off + (long)c * 16384;
    u16x8 sb;
#pragma unroll
    for (int j = 0; j < 8; j++) sb[j] = f2bf(s[j]);
    *(u16x8*)(S_all + idx) = sb;
    u16x8 ub = *(const u16x8*)(U + idx);
#pragma unroll
    for (int j = 0; j < 8; j++) s[j] = lamC * s[j] + bf2f(ub[j]);
  }
}

// ---------------- fused per-(b,h,c) attention output + gated RMSNorm ----------------
// gate input is PRE-SIGMOIDED (fused into gate GEMM epilogue, rot=2).
__global__ __launch_bounds__(256, 2) void attn_out(
    const u16* __restrict__ qkv, const u16* __restrict__ vT,
    const u16* __restrict__ S_all, const u16* __restrict__ gate,
    const float* __restrict__ nw, u16* __restrict__ nrm) {
  __shared__ u16 sA[128 * 32], sB[128 * 32], sK[128 * 32];
  __shared__ u16 sS[128 * 136]; // stride 136: breaks 16-way bank conflict
  __shared__ float sNorm[2][128];
  const int blk = blockIdx.x;
  const int bh = blk >> 4, c = blk & 15;
  const int b = bh >> 4, h = bh & 15;
  const float log_lam = -exp2f(-0.5f * (float)(h + 1));
  const int tid = threadIdx.x, lane = tid & 63, wid = tid >> 6;
  const int wm = (wid & 1) * 64, wn = (wid >> 1) * 64;
  const int fm = lane & 15, fq = lane >> 4, kq = lane >> 4;
  const int lr = lane >> 2;
  const int ak = (((lane & 3) - ((lane >> 3) & 3)) & 3) * 8;
  const int ch0 = wid * 2, ch1 = ch0 + 1;
  const int r0 = ch0 * 16 + lr, r1 = ch1 * 16 + lr;
  const int qs = ((kq + (fm >> 1)) & 3) * 8;
  const int aoff = (wm >> 4) * 512 + fm * 32 + qs;
  const int boff = (wn >> 4) * 512 + fm * 32 + qs;
  const u16* qbase = qkv + (long)(b * 2048 + c * 128) * 6272 + h * 128; // rows t, stride 6272
  const u16* kbase = qbase + 2048;                                     // rows s
  const u16* Sbase = S_all + ((long)bh * 16 + c) * 16384;              // [e][d], stride 128
  const u16* vbase = vT + (long)bh * 262144 + (long)c * 128;           // rows e, stride 2048

  f32x4 acc[4][4] = {}; // o_inter, then O total
  f32x4 sc[4][4] = {};  // scores
  // Phase 1+2: o_inter = Q @ S_c   and   scores = Q @ K^T (shared Q staging)
  for (int kb = 0; kb < 128; kb += 32) {
    async16(qbase + (long)r0 * 6272 + kb + ak, sA + ch0 * 512);
    async16(qbase + (long)r1 * 6272 + kb + ak, sA + ch1 * 512);
    async16(Sbase + r0 * 128 + kb + ak, sB + ch0 * 512);
    async16(Sbase + r1 * 128 + kb + ak, sB + ch1 * 512);
    async16(kbase + (long)r0 * 6272 + kb + ak, sK + ch0 * 512);
    async16(kbase + (long)r1 * 6272 + kb + ak, sK + ch1 * 512);
    __syncthreads();
    bf16x8 aq[4], bs[4], bk[4];
#pragma unroll
    for (int i = 0; i < 4; i++) {
      aq[i] = *(const bf16x8*)&sA[aoff + i * 512];
      bs[i] = *(const bf16x8*)&sB[boff + i * 512];
      bk[i] = *(const bf16x8*)&sK[boff + i * 512];
    }
#pragma unroll
    for (int mt = 0; mt < 4; mt++)
#pragma unroll
      for (int nt = 0; nt < 4; nt++) {
        acc[mt][nt] = __builtin_amdgcn_mfma_f32_16x16x32_bf16(aq[mt], bs[nt], acc[mt][nt], 0, 0, 0);
        sc[mt][nt] = __builtin_amdgcn_mfma_f32_16x16x32_bf16(aq[mt], bk[nt], sc[mt][nt], 0, 0, 0);
      }
    __syncthreads();
  }
  // scale o_inter rows by decay_q(t) = exp(log_lam*(t+1))
#pragma unroll
  for (int mt = 0; mt < 4; mt++)
#pragma unroll
    for (int r = 0; r < 4; r++) {
      int t = wm + mt * 16 + fq * 4 + r;
      float d = __expf(log_lam * (float)(t + 1));
#pragma unroll
      for (int nt = 0; nt < 4; nt++) acc[mt][nt][r] *= d;
    }
  // mask+decay scores, write bf16 to sS[t][s].
  // e^{lam*(t-s)} factored: eT(t)*eS(s); both finite on all SELECTED lanes
  // (worst valid pair e^{+44.5} * e^{-44.5}; masked lanes may see inf,
  // discarded by the select).
  float eS[4];
#pragma unroll
  for (int nt = 0; nt < 4; nt++)
    eS[nt] = __expf(log_lam * (float)(63 - (nt * 16 + fm)));
#pragma unroll
  for (int mt = 0; mt < 4; mt++)
#pragma unroll
    for (int r = 0; r < 4; r++) {
      int t = wm + mt * 16 + fq * 4 + r;
      float eT = __expf(log_lam * (float)(t - wn - 63));
#pragma unroll
      for (int nt = 0; nt < 4; nt++) {
        int s = wn + nt * 16 + fm;
        float v = sc[mt][nt][r];
        v = (t >= s) ? v * (eT * eS[nt]) : 0.f;
        sS[t * 136 + s] = f2bf(v);
      }
    }
  __syncthreads();
  // Phase 3: O += scores @ V   (A from sS, B staged from vT)
  for (int kb = 0; kb < 128; kb += 32) {
    async16(vbase + r0 * 2048 + kb + ak, sB + ch0 * 512);
    async16(vbase + r1 * 2048 + kb + ak, sB + ch1 * 512);
    __syncthreads();
    bf16x8 as[4], bv[4];
#pragma unroll
    for (int i = 0; i < 4; i++) {
      as[i] = *(const bf16x8*)&sS[(wm + i * 16 + fm) * 136 + kb + kq * 8];
      bv[i] = *(const bf16x8*)&sB[boff + i * 512];
    }
#pragma unroll
    for (int mt = 0; mt < 4; mt++)
#pragma unroll
      for (int nt = 0; nt < 4; nt++)
        acc[mt][nt] = __builtin_amdgcn_mfma_f32_16x16x32_bf16(as[mt], bv[nt], acc[mt][nt], 0, 0, 0);
    __syncthreads();
  }
  // ---- fused gated group-RMSNorm: x = O*gate (gate pre-sigmoided) ----
  const u16* gbase = gate + (long)(b * 2048 + c * 128) * 2048 + h * 128;
  float nwv[4];
#pragma unroll
  for (int nt = 0; nt < 4; nt++) nwv[nt] = nw[h * 128 + wn + nt * 16 + fm];
  float part[4][4];
#pragma unroll
  for (int mt = 0; mt < 4; mt++)
#pragma unroll
    for (int r = 0; r < 4; r++) {
      int t = wm + mt * 16 + fq * 4 + r;
      float p = 0.f;
#pragma unroll
      for (int nt = 0; nt < 4; nt++) {
        int e = wn + nt * 16 + fm;
        float g = bf2f(gbase[(long)t * 2048 + e]);
        float x = acc[mt][nt][r] * g;
        acc[mt][nt][r] = x;
        p += x * x;
      }
      part[mt][r] = p;
    }
#pragma unroll
  for (int o = 1; o < 16; o <<= 1)
#pragma unroll
    for (int mt = 0; mt < 4; mt++)
#pragma unroll
      for (int r = 0; r < 4; r++) part[mt][r] += __shfl_xor(part[mt][r], o);
  if (fm == 0) {
#pragma unroll
    for (int mt = 0; mt < 4; mt++)
#pragma unroll
      for (int r = 0; r < 4; r++)
        sNorm[wid >> 1][wm + mt * 16 + fq * 4 + r] = part[mt][r];
  }
  __syncthreads();
  long orow0 = (long)(b * 2048 + c * 128);
#pragma unroll
  for (int mt = 0; mt < 4; mt++)
#pragma unroll
    for (int r = 0; r < 4; r++) {
      int t = wm + mt * 16 + fq * 4 + r;
      float ms = (sNorm[0][t] + sNorm[1][t]) * (1.f / 128.f);
      float rs = rsqrtf(ms + 1e-6f);
#pragma unroll
      for (int nt = 0; nt < 4; nt++) {
        int e = wn + nt * 16 + fm;
        nrm[(orow0 + t) * 2048 + h * 128 + e] = f2bf(acc[mt][nt][r] * rs * nwv[nt]);
      }
    }
}

// ---------------- host ----------------
extern "C" void kernel_launch(void* const* d_in, const int* in_sizes, int n_in,
                              void* d_out, int out_size, void* d_ws, size_t ws_size,
                              hipStream_t stream) {
  (void)in_sizes; (void)n_in; (void)out_size; (void)ws_size;
  const float* x   = (const float*)d_in[0];
  const float* Wq  = (const float*)d_in[1];
  const float* Wk  = (const float*)d_in[2];
  const float* Wv  = (const float*)d_in[3];
  const float* Wo  = (const float*)d_in[4];
  const float* Wg1 = (const float*)d_in[5];
  const float* Wg2 = (const float*)d_in[6];
  const float* nw  = (const float*)d_in[7];
  float* out = (float*)d_out;

  char* ws = (char*)d_ws;
  size_t off = 0;
  auto alloc = [&](size_t bytes) -> void* {
    void* p = ws + off;
    off += (bytes + 255) & ~(size_t)255;
    return p;
  };
  u16* xb    = (u16*)alloc(4096UL * 2048 * 2);
  u16* wtqkv = (u16*)alloc(6272UL * 2048 * 2); // [Wq^T perm | Wk^T perm | Wv^T | Wg1^T]
  u16* wot   = (u16*)alloc(2048UL * 2048 * 2);
  u16* wg2t  = (u16*)alloc(2048UL * 128 * 2);
  u16* qkvg  = (u16*)alloc(4096UL * 6272 * 2); // q(rot) | k(rot) | (v unused) | g1
  u16* gate  = (u16*)alloc(4096UL * 2048 * 2);
  u16* kdT   = (u16*)alloc(32UL * 128 * 2048 * 2);
  u16* vT    = (u16*)alloc(32UL * 128 * 2048 * 2);
  u16* Ubuf  = (u16*)alloc(512UL * 16384 * 2);
  u16* S_all = (u16*)alloc(512UL * 16384 * 2);
  u16* nrm   = (u16*)alloc(4096UL * 2048 * 2);
  float* rope = (float*)alloc(2048UL * 64 * 8); // float2 [t][jj]

  // 1. prep: x conversion, weight transposes, rope LUT (one launch)
  prep_all<<<dim3(25600), dim3(256), 0, stream>>>(x, Wq, Wk, Wv, Wo, Wg1, Wg2,
                                                  xb, wtqkv, wot, wg2t, rope);
  // 2. QKV+g1 projection: silu+rotate (LUT) on q,k; v stored transposed to vT
  gemm_bt<u16><<<dim3(49, 32, 1), dim3(256), 0, stream>>>(xb, wtqkv, qkvg,
      4096, 6272, 2048, 2048, 2048, 6272, 1, 1, 0, 0, 0, 0, 0, 0, rope, vT);
  // gate = sigmoid(g1 @ Wg2^T)  (sigmoid fused, rot=2)
  gemm_bt<u16><<<dim3(16, 32, 1), dim3(256), 0, stream>>>(qkvg + 6144, wg2t, gate,
      4096, 2048, 128, 6272, 128, 2048, 2, 1, 0, 0, 0, 0, 0, 0, nullptr, nullptr);
  // 3. attention
  transpose_k<<<dim3(64, 4, 32), dim3(256), 0, stream>>>(qkvg, kdT);
  gemm_bt<u16><<<dim3(1, 1, 512), dim3(256), 0, stream>>>(vT, kdT, Ubuf,
      128, 128, 128, 2048, 2048, 128, 0,
      16, 262144L, 128L, 262144L, 128L, 262144L, 16384L, nullptr, nullptr);
  scan_state<<<dim3(256), dim3(256), 0, stream>>>(Ubuf, S_all);
  attn_out<<<dim3(512), dim3(256), 0, stream>>>(qkvg, vT, S_all, gate, nw, nrm);
  // 4. output projection
  gemm_bt<float><<<dim3(16, 32, 1), dim3(256), 0, stream>>>(nrm, wot, out,
      4096, 2048, 2048, 2048, 2048, 2048, 0, 1, 0, 0, 0, 0, 0, 0, nullptr, nullptr);
}

// Round 9
// 380.104 us; speedup vs baseline: 1.1043x; 1.0486x over previous
//
#include <hip/hip_runtime.h>

// LinearAttention forward on gfx950.
// R4:  Wg1 folded into QKV GEMM; silu+rotate fused into QKV epilogue via
//      permuted q/k weight columns; gated RMSNorm fused into attn_out.
// R8:  sigmoid fused into gate GEMM; factored score-decay exp; attn_out 2/CU.
// R10: rope LUT; v stored transposed into vT from QKV epilogue; merged prep.
// R12: register-cliff fix: gemm_bt launch_bounds(256,4) (combined<=128);
//      sV overlays sA/sB in one 16KB smem block (XOR swizzle).  (398.6 us)
// R13: k-transpose+decay fused into QKV epilogue (same sV mechanism as v;
//      kills transpose_k dispatch + 32MB traffic); gate GEMM fused into
//      attn_out as 4th MFMA phase (gsc reuses dead sc regs; kills gate
//      dispatch + 32MB traffic). 6 dispatches.

#define DEV __device__ __forceinline__
typedef unsigned short u16;
typedef __bf16 bf16x8 __attribute__((ext_vector_type(8)));
typedef float f32x4 __attribute__((ext_vector_type(4)));
typedef u16 u16x8 __attribute__((ext_vector_type(8)));
typedef u16 u16x4 __attribute__((ext_vector_type(4)));

DEV u16 f2bf(float f) {
  unsigned u = __builtin_bit_cast(unsigned, f);
  u += 0x7fffu + ((u >> 16) & 1u);
  return (u16)(u >> 16);
}
DEV float bf2f(u16 h) {
  unsigned u = ((unsigned)h) << 16;
  return __builtin_bit_cast(float, u);
}
DEV void async16(const u16* g, u16* l) {
  __builtin_amdgcn_global_load_lds(
      (const __attribute__((address_space(1))) unsigned int*)g,
      (__attribute__((address_space(3))) unsigned int*)l, 16, 0, 0);
}

// ---------------- prep: x->bf16 | weight transposes | rope LUT ----------------
__global__ void prep_all(const float* __restrict__ x,
                         const float* __restrict__ Wq, const float* __restrict__ Wk,
                         const float* __restrict__ Wv, const float* __restrict__ Wo,
                         const float* __restrict__ Wg1, const float* __restrict__ Wg2,
                         u16* __restrict__ xb, u16* __restrict__ wtqkvg,
                         u16* __restrict__ wot, u16* __restrict__ wg2t,
                         float* __restrict__ rope) {
  int id = blockIdx.x;
  if (id < 8192) {
    long i = ((long)id * 256 + threadIdx.x) * 4;
    float4 v = *(const float4*)(x + i);
    ushort4 p;
    p.x = f2bf(v.x); p.y = f2bf(v.y); p.z = f2bf(v.z); p.w = f2bf(v.w);
    *(ushort4*)(xb + i) = p;
    return;
  }
  if (id >= 25088) {
    int idx = (id - 25088) * 256 + threadIdx.x;  // 131072 = 2048 t x 64 jj
    int t = idx >> 6, jj = idx & 63;
    float th = exp2f(-13.287712379549449f * (float)jj * (1.f / 64.f));
    float sn, cs;
    sincosf((float)t * th, &sn, &cs);
    ((float2*)rope)[idx] = make_float2(cs, sn);
    return;
  }
  id -= 8192;
  __shared__ float t[32][33];
  const float* in; u16* out; int K, N, bx, by;
  bool perm = false;
  if (id < 12288) {
    int w = id >> 12, tt = id & 4095;
    in = (w == 0) ? Wq : (w == 1) ? Wk : Wv;
    out = wtqkvg + (long)w * 2048 * 2048;
    K = 2048; N = 2048; bx = tt & 63; by = tt >> 6;
    perm = (w < 2);
  } else if (id < 16384) {
    int tt = id - 12288;
    in = Wo; out = wot; K = 2048; N = 2048; bx = tt & 63; by = tt >> 6;
  } else if (id < 16640) {
    int tt = id - 16384;
    in = Wg1; out = wtqkvg + 6144L * 2048; K = 2048; N = 128; bx = tt & 3; by = tt >> 2;
  } else {
    int tt = id - 16640;
    in = Wg2; out = wg2t; K = 128; N = 2048; bx = tt & 63; by = tt >> 6;
  }
  int c = threadIdx.x & 31, r0 = threadIdx.x >> 5;
  for (int r = r0; r < 32; r += 8)
    t[r][c] = in[(long)(by * 32 + r) * N + bx * 32 + c];
  __syncthreads();
  for (int r = r0; r < 32; r += 8) {
    int n = bx * 32 + r, nr = n;
    if (perm) {
      int h = n >> 7, j = n & 127, jj = j & 63, hi = j >> 6;
      nr = h * 128 + (jj & 15) + 32 * (jj >> 4) + 16 * hi;
    }
    out[(long)nr * K + by * 32 + c] = f2bf(t[c][r]);
  }
}

// ---------------- GEMM: C[M][N] = A[M][K] @ B^T, B stored [N][K], bf16 in ----------------
// rot=1: cols<2048 q: silu+rotate rows. cols [2048,4096) k: silu+rotate rows
//        AND decayed transpose into KT (sV overlay staging, 2 half-passes).
//        cols [4096,6144) v: transpose into VT (sV overlay). >=6144 generic.
template <typename OutT>
__global__ __launch_bounds__(256, 4) void gemm_bt(
    const u16* __restrict__ A, const u16* __restrict__ B, OutT* __restrict__ C,
    int M, int N, int K, int lda, int ldb, int ldc, int rot,
    int nc, long sA1, long sA2, long sB1, long sB2, long sC1, long sC2,
    const float* __restrict__ rope, u16* __restrict__ VT, u16* __restrict__ KT) {
  __shared__ u16 smem[8192];  // sA[0:4096] | sB[4096:8192]; reused as sV[64][128]
  u16* const sA = smem;
  u16* const sB = smem + 4096;
  {
    int z = blockIdx.z, z1 = z / nc, z2 = z % nc;
    A += z1 * sA1 + z2 * sA2;
    B += z1 * sB1 + z2 * sB2;
    C += z1 * sC1 + z2 * sC2;
  }
  int bxs, bys;
  {
    int lin = blockIdx.x + gridDim.x * blockIdx.y;
    int per = 16 * gridDim.y;
    int g = lin / per, r = lin % per;
    int base = g * 16;
    int w = min(16, (int)gridDim.x - base);
    bxs = base + r % w; bys = r / w;
  }
  const int tid = threadIdx.x, lane = tid & 63, wid = tid >> 6;
  const int bm = bys * 128, bn = bxs * 128;
  const int ch0 = wid * 2, ch1 = ch0 + 1;
  const int lr = lane >> 2;                                  // local row 0..15
  const int ak = (((lane & 3) - ((lane >> 3) & 3)) & 3) * 8; // rotated k-piece
  const int ar0 = ch0 * 16 + lr, ar1 = ch1 * 16 + lr;
  const u16* gA0 = A + (long)(bm + ar0) * lda + ak;
  const u16* gA1 = A + (long)(bm + ar1) * lda + ak;
  const u16* gB0 = B + (long)(bn + ar0) * ldb + ak;
  const u16* gB1 = B + (long)(bn + ar1) * ldb + ak;
  u16* lA0 = sA + ch0 * 512; u16* lA1 = sA + ch1 * 512;
  u16* lB0 = sB + ch0 * 512; u16* lB1 = sB + ch1 * 512;
  const int wm = (wid & 1) * 64, wn = (wid >> 1) * 64;
  const int fm = lane & 15, kq = lane >> 4;
  const int qs = ((kq + (fm >> 1)) & 3) * 8;
  const int aoff = (wm >> 4) * 512 + fm * 32 + qs;
  const int boff = (wn >> 4) * 512 + fm * 32 + qs;
  f32x4 acc[4][4] = {};
  for (int kb = 0; kb < K; kb += 32) {
    async16(gA0, lA0); async16(gA1, lA1);
    async16(gB0, lB0); async16(gB1, lB1);
    gA0 += 32; gA1 += 32; gB0 += 32; gB1 += 32;
    __syncthreads();
    bf16x8 af[4], bfr[4];
#pragma unroll
    for (int i = 0; i < 4; i++) af[i] = *(const bf16x8*)&sA[aoff + i * 512];
#pragma unroll
    for (int i = 0; i < 4; i++) bfr[i] = *(const bf16x8*)&sB[boff + i * 512];
#pragma unroll
    for (int mt = 0; mt < 4; mt++)
#pragma unroll
      for (int nt = 0; nt < 4; nt++)
        acc[mt][nt] = __builtin_amdgcn_mfma_f32_16x16x32_bf16(af[mt], bfr[nt], acc[mt][nt], 0, 0, 0);
    __syncthreads();
  }
  const int cr = (lane >> 4) * 4;
  if constexpr (sizeof(OutT) == 2) {
    if (rot == 1 && bn < 4096) {
      // silu + rotate epilogue via rope LUT; lane holds permuted cols.
#pragma unroll
      for (int mt = 0; mt < 4; mt++)
#pragma unroll
        for (int r = 0; r < 4; r++) {
          long row = bm + wm + mt * 16 + cr + r;
          const float2* rp = (const float2*)rope + (long)(row & 2047) * 64;
#pragma unroll
          for (int np = 0; np < 4; np += 2) {
            float x1 = acc[mt][np][r], x2 = acc[mt][np + 1][r];
            x1 = x1 / (1.f + __expf(-x1));
            x2 = x2 / (1.f + __expf(-x2));
            int jj = fm + 16 * ((wn >> 5) + (np >> 1));
            float2 cn = rp[jj];
            C[row * ldc + bn + jj]      = f2bf(x1 * cn.x - x2 * cn.y);
            C[row * ldc + bn + 64 + jj] = f2bf(x1 * cn.y + x2 * cn.x);
          }
        }
      if (bn >= 2048) {
        // k: additionally store decayed transpose KT[(b*16+h)*128+d][n].
        const int head = (bn - 2048) >> 7;
        const int bq = bm >> 11, tb = bm & 2047;
        const float llk = -exp2f(-0.5f * (float)(head + 1));
        const float em = __expf(-llk);
        u16* kt = KT + (long)(bq * 16 + head) * 128 * 2048 + tb;
        u16* const sV = smem;
#pragma unroll
        for (int half = 0; half < 2; half++) {
          __syncthreads();
#pragma unroll
          for (int mt = 0; mt < 4; mt++) {
            int t0 = wm + mt * 16 + cr;
            float d0 = __expf(llk * (float)(127 - t0));
#pragma unroll
            for (int np = 0; np < 4; np += 2) {
              int jj = fm + 16 * ((wn >> 5) + (np >> 1));
              u16x4 pk;
              float dd = d0;
#pragma unroll
              for (int r = 0; r < 4; r++) {
                long row = bm + t0 + r;
                float2 cn = ((const float2*)rope)[(long)(row & 2047) * 64 + jj];
                float x1 = acc[mt][np][r], x2 = acc[mt][np + 1][r];
                x1 = x1 / (1.f + __expf(-x1));
                x2 = x2 / (1.f + __expf(-x2));
                float y = (half == 0) ? (x1 * cn.x - x2 * cn.y)
                                      : (x1 * cn.y + x2 * cn.x);
                pk[r] = f2bf(y * dd);
                dd *= em;
              }
              *(u16x4*)&sV[jj * 128 + (t0 ^ ((jj & 15) << 3))] = pk;
            }
          }
          __syncthreads();
#pragma unroll
          for (int it = 0; it < 4; it++) {
            int dl = it * 16 + (tid >> 4);
            int tc = (tid & 15) * 8;
            u16x8 vv = *(const u16x8*)&sV[dl * 128 + (tc ^ ((dl & 15) << 3))];
            *(u16x8*)(kt + (long)(half * 64 + dl) * 2048 + tc) = vv;
          }
        }
      }
      return;
    }
    if (rot == 1 && bn < 6144) {
      // v block: 128t x 128d of one (b,h). Transpose via sV (= smem overlay,
      // XOR-swizzled [64][128]) per d-half; stores 16B-contig into vT.
      const int bq = bm >> 11;
      const int head = (bn - 4096) >> 7;
      const int tb = bm & 2047;
      u16* vbase = VT + (long)(bq * 16 + head) * 128 * 2048 + tb;
      u16* const sV = smem;
#pragma unroll
      for (int dh = 0; dh < 2; dh++) {
        __syncthreads();
        if ((wid >> 1) == dh) {
#pragma unroll
          for (int mt = 0; mt < 4; mt++)
#pragma unroll
            for (int nt = 0; nt < 4; nt++) {
              int dl = nt * 16 + fm;
              int t0 = wm + mt * 16 + cr;
              u16x4 pk;
#pragma unroll
              for (int r = 0; r < 4; r++) pk[r] = f2bf(acc[mt][nt][r]);
              *(u16x4*)&sV[dl * 128 + (t0 ^ ((fm & 15) << 3))] = pk;
            }
        }
        __syncthreads();
#pragma unroll
        for (int it = 0; it < 4; it++) {
          int dl = it * 16 + (tid >> 4);
          int tc = (tid & 15) * 8;
          u16x8 vv = *(const u16x8*)&sV[dl * 128 + (tc ^ ((dl & 15) << 3))];
          *(u16x8*)(vbase + (long)(dh * 64 + dl) * 2048 + tc) = vv;
        }
      }
      return;
    }
  }
#pragma unroll
  for (int mt = 0; mt < 4; mt++)
#pragma unroll
    for (int nt = 0; nt < 4; nt++)
#pragma unroll
      for (int r = 0; r < 4; r++) {
        long row = bm + wm + mt * 16 + cr + r;
        long col = bn + wn + nt * 16 + fm;
        float v = acc[mt][nt][r];
        if constexpr (sizeof(OutT) == 2) C[row * ldc + col] = f2bf(v);
        else                             C[row * ldc + col] = v;
      }
}

// ---------------- decay scan over chunks: S_c = lamC*S_{c-1} + U_{c-1}, S_0 = 0 ----------------
__global__ void scan_state(const u16* __restrict__ U, u16* __restrict__ S_all) {
  int blk = blockIdx.x; // 256 blocks: [bh:32][slice:8]
  int bh = blk >> 3, sl = blk & 7, h = bh & 15;
  float log_lam = -exp2f(-0.5f * (float)(h + 1));
  float lamC = expf(log_lam * 128.f);
  long off = (long)bh * 16 * 16384 + sl * 2048 + threadIdx.x * 8;
  float s[8];
#pragma unroll
  for (int j = 0; j < 8; j++) s[j] = 0.f;
  for (int c = 0; c < 16; c++) {
    long idx = off + (long)c * 16384;
    u16x8 sb;
#pragma unroll
    for (int j = 0; j < 8; j++) sb[j] = f2bf(s[j]);
    *(u16x8*)(S_all + idx) = sb;
    u16x8 ub = *(const u16x8*)(U + idx);
#pragma unroll
    for (int j = 0; j < 8; j++) s[j] = lamC * s[j] + bf2f(ub[j]);
  }
}

// ---------------- fused per-(b,h,c) attention output + gate GEMM + gated RMSNorm ----------------
__global__ __launch_bounds__(256, 2) void attn_out(
    const u16* __restrict__ qkv, const u16* __restrict__ vT,
    const u16* __restrict__ S_all, const u16* __restrict__ wg2t,
    const float* __restrict__ nw, u16* __restrict__ nrm) {
  __shared__ u16 sA[128 * 32], sB[128 * 32], sK[128 * 32];
  __shared__ u16 sS[128 * 136]; // stride 136: breaks 16-way bank conflict
  __shared__ float sNorm[2][128];
  const int blk = blockIdx.x;
  const int bh = blk >> 4, c = blk & 15;
  const int b = bh >> 4, h = bh & 15;
  const float log_lam = -exp2f(-0.5f * (float)(h + 1));
  const int tid = threadIdx.x, lane = tid & 63, wid = tid >> 6;
  const int wm = (wid & 1) * 64, wn = (wid >> 1) * 64;
  const int fm = lane & 15, fq = lane >> 4, kq = lane >> 4;
  const int lr = lane >> 2;
  const int ak = (((lane & 3) - ((lane >> 3) & 3)) & 3) * 8;
  const int ch0 = wid * 2, ch1 = ch0 + 1;
  const int r0 = ch0 * 16 + lr, r1 = ch1 * 16 + lr;
  const int qs = ((kq + (fm >> 1)) & 3) * 8;
  const int aoff = (wm >> 4) * 512 + fm * 32 + qs;
  const int boff = (wn >> 4) * 512 + fm * 32 + qs;
  const u16* qbase = qkv + (long)(b * 2048 + c * 128) * 6272 + h * 128; // rows t, stride 6272
  const u16* kbase = qbase + 2048;                                     // rows s
  const u16* g1base = qkv + (long)(b * 2048 + c * 128) * 6272 + 6144;  // rows t, K=128
  const u16* Sbase = S_all + ((long)bh * 16 + c) * 16384;              // [e][d], stride 128
  const u16* vbase = vT + (long)bh * 262144 + (long)c * 128;           // rows e, stride 2048
  const u16* wbase = wg2t + (long)(h * 128) * 128;                     // rows e, K=128

  f32x4 acc[4][4] = {}; // o_inter, then O total
  f32x4 sc[4][4] = {};  // scores
  // Phase 1+2: o_inter = Q @ S_c   and   scores = Q @ K^T (shared Q staging)
  for (int kb = 0; kb < 128; kb += 32) {
    async16(qbase + (long)r0 * 6272 + kb + ak, sA + ch0 * 512);
    async16(qbase + (long)r1 * 6272 + kb + ak, sA + ch1 * 512);
    async16(Sbase + r0 * 128 + kb + ak, sB + ch0 * 512);
    async16(Sbase + r1 * 128 + kb + ak, sB + ch1 * 512);
    async16(kbase + (long)r0 * 6272 + kb + ak, sK + ch0 * 512);
    async16(kbase + (long)r1 * 6272 + kb + ak, sK + ch1 * 512);
    __syncthreads();
    bf16x8 aq[4], bs[4], bk[4];
#pragma unroll
    for (int i = 0; i < 4; i++) {
      aq[i] = *(const bf16x8*)&sA[aoff + i * 512];
      bs[i] = *(const bf16x8*)&sB[boff + i * 512];
      bk[i] = *(const bf16x8*)&sK[boff + i * 512];
    }
#pragma unroll
    for (int mt = 0; mt < 4; mt++)
#pragma unroll
      for (int nt = 0; nt < 4; nt++) {
        acc[mt][nt] = __builtin_amdgcn_mfma_f32_16x16x32_bf16(aq[mt], bs[nt], acc[mt][nt], 0, 0, 0);
        sc[mt][nt] = __builtin_amdgcn_mfma_f32_16x16x32_bf16(aq[mt], bk[nt], sc[mt][nt], 0, 0, 0);
      }
    __syncthreads();
  }
  // scale o_inter rows by decay_q(t) = exp(log_lam*(t+1))
#pragma unroll
  for (int mt = 0; mt < 4; mt++)
#pragma unroll
    for (int r = 0; r < 4; r++) {
      int t = wm + mt * 16 + fq * 4 + r;
      float d = __expf(log_lam * (float)(t + 1));
#pragma unroll
      for (int nt = 0; nt < 4; nt++) acc[mt][nt][r] *= d;
    }
  // mask+decay scores, write bf16 to sS[t][s] (factored exp; masked lanes'
  // possible inf discarded by the select).
  float eS[4];
#pragma unroll
  for (int nt = 0; nt < 4; nt++)
    eS[nt] = __expf(log_lam * (float)(63 - (nt * 16 + fm)));
#pragma unroll
  for (int mt = 0; mt < 4; mt++)
#pragma unroll
    for (int r = 0; r < 4; r++) {
      int t = wm + mt * 16 + fq * 4 + r;
      float eT = __expf(log_lam * (float)(t - wn - 63));
#pragma unroll
      for (int nt = 0; nt < 4; nt++) {
        int s = wn + nt * 16 + fm;
        float v = sc[mt][nt][r];
        v = (t >= s) ? v * (eT * eS[nt]) : 0.f;
        sS[t * 136 + s] = f2bf(v);
      }
    }
  __syncthreads();
  // Phase 3: O += scores @ V   (A from sS, B staged from vT)
  for (int kb = 0; kb < 128; kb += 32) {
    async16(vbase + r0 * 2048 + kb + ak, sB + ch0 * 512);
    async16(vbase + r1 * 2048 + kb + ak, sB + ch1 * 512);
    __syncthreads();
    bf16x8 as[4], bv[4];
#pragma unroll
    for (int i = 0; i < 4; i++) {
      as[i] = *(const bf16x8*)&sS[(wm + i * 16 + fm) * 136 + kb + kq * 8];
      bv[i] = *(const bf16x8*)&sB[boff + i * 512];
    }
#pragma unroll
    for (int mt = 0; mt < 4; mt++)
#pragma unroll
      for (int nt = 0; nt < 4; nt++)
        acc[mt][nt] = __builtin_amdgcn_mfma_f32_16x16x32_bf16(as[mt], bv[nt], acc[mt][nt], 0, 0, 0);
    __syncthreads();
  }
  // Phase 4: gate = g1 @ Wg2t^T (head h cols); gsc reuses dead sc registers.
  f32x4 gsc[4][4] = {};
  for (int kb = 0; kb < 128; kb += 32) {
    async16(g1base + (long)r0 * 6272 + kb + ak, sA + ch0 * 512);
    async16(g1base + (long)r1 * 6272 + kb + ak, sA + ch1 * 512);
    async16(wbase + r0 * 128 + kb + ak, sB + ch0 * 512);
    async16(wbase + r1 * 128 + kb + ak, sB + ch1 * 512);
    __syncthreads();
    bf16x8 ag[4], bw[4];
#pragma unroll
    for (int i = 0; i < 4; i++) {
      ag[i] = *(const bf16x8*)&sA[aoff + i * 512];
      bw[i] = *(const bf16x8*)&sB[boff + i * 512];
    }
#pragma unroll
    for (int mt = 0; mt < 4; mt++)
#pragma unroll
      for (int nt = 0; nt < 4; nt++)
        gsc[mt][nt] = __builtin_amdgcn_mfma_f32_16x16x32_bf16(ag[mt], bw[nt], gsc[mt][nt], 0, 0, 0);
    __syncthreads();
  }
  // ---- fused gated group-RMSNorm: x = O*sigmoid(gate) ----
  float nwv[4];
#pragma unroll
  for (int nt = 0; nt < 4; nt++) nwv[nt] = nw[h * 128 + wn + nt * 16 + fm];
  float part[4][4];
#pragma unroll
  for (int mt = 0; mt < 4; mt++)
#pragma unroll
    for (int r = 0; r < 4; r++) {
      float p = 0.f;
#pragma unroll
      for (int nt = 0; nt < 4; nt++) {
        float g = 1.f / (1.f + __expf(-gsc[mt][nt][r]));
        float x = acc[mt][nt][r] * g;
        acc[mt][nt][r] = x;
        p += x * x;
      }
      part[mt][r] = p;
    }
#pragma unroll
  for (int o = 1; o < 16; o <<= 1)
#pragma unroll
    for (int mt = 0; mt < 4; mt++)
#pragma unroll
      for (int r = 0; r < 4; r++) part[mt][r] += __shfl_xor(part[mt][r], o);
  if (fm == 0) {
#pragma unroll
    for (int mt = 0; mt < 4; mt++)
#pragma unroll
      for (int r = 0; r < 4; r++)
        sNorm[wid >> 1][wm + mt * 16 + fq * 4 + r] = part[mt][r];
  }
  __syncthreads();
  long orow0 = (long)(b * 2048 + c * 128);
#pragma unroll
  for (int mt = 0; mt < 4; mt++)
#pragma unroll
    for (int r = 0; r < 4; r++) {
      int t = wm + mt * 16 + fq * 4 + r;
      float ms = (sNorm[0][t] + sNorm[1][t]) * (1.f / 128.f);
      float rs = rsqrtf(ms + 1e-6f);
#pragma unroll
      for (int nt = 0; nt < 4; nt++) {
        int e = wn + nt * 16 + fm;
        nrm[(orow0 + t) * 2048 + h * 128 + e] = f2bf(acc[mt][nt][r] * rs * nwv[nt]);
      }
    }
}

// ---------------- host ----------------
extern "C" void kernel_launch(void* const* d_in, const int* in_sizes, int n_in,
                              void* d_out, int out_size, void* d_ws, size_t ws_size,
                              hipStream_t stream) {
  (void)in_sizes; (void)n_in; (void)out_size; (void)ws_size;
  const float* x   = (const float*)d_in[0];
  const float* Wq  = (const float*)d_in[1];
  const float* Wk  = (const float*)d_in[2];
  const float* Wv  = (const float*)d_in[3];
  const float* Wo  = (const float*)d_in[4];
  const float* Wg1 = (const float*)d_in[5];
  const float* Wg2 = (const float*)d_in[6];
  const float* nw  = (const float*)d_in[7];
  float* out = (float*)d_out;

  char* ws = (char*)d_ws;
  size_t off = 0;
  auto alloc = [&](size_t bytes) -> void* {
    void* p = ws + off;
    off += (bytes + 255) & ~(size_t)255;
    return p;
  };
  u16* xb    = (u16*)alloc(4096UL * 2048 * 2);
  u16* wtqkv = (u16*)alloc(6272UL * 2048 * 2); // [Wq^T perm | Wk^T perm | Wv^T | Wg1^T]
  u16* wot   = (u16*)alloc(2048UL * 2048 * 2);
  u16* wg2t  = (u16*)alloc(2048UL * 128 * 2);
  u16* qkvg  = (u16*)alloc(4096UL * 6272 * 2); // q(rot) | k(rot) | (v slot unused) | g1
  u16* kdT   = (u16*)alloc(32UL * 128 * 2048 * 2);
  u16* vT    = (u16*)alloc(32UL * 128 * 2048 * 2);
  u16* Ubuf  = (u16*)alloc(512UL * 16384 * 2);
  u16* S_all = (u16*)alloc(512UL * 16384 * 2);
  u16* nrm   = (u16*)alloc(4096UL * 2048 * 2);
  float* rope = (float*)alloc(2048UL * 64 * 8); // float2 [t][jj]

  // 1. prep: x conversion, weight transposes, rope LUT (one launch)
  prep_all<<<dim3(25600), dim3(256), 0, stream>>>(x, Wq, Wk, Wv, Wo, Wg1, Wg2,
                                                  xb, wtqkv, wot, wg2t, rope);
  // 2. QKV+g1 projection: silu+rotate on q,k; k also -> kdT (decayed); v -> vT
  gemm_bt<u16><<<dim3(49, 32, 1), dim3(256), 0, stream>>>(xb, wtqkv, qkvg,
      4096, 6272, 2048, 2048, 2048, 6272, 1, 1, 0, 0, 0, 0, 0, 0, rope, vT, kdT);
  // 3. attention: U per chunk, scan, fused output+gate+RMSNorm
  gemm_bt<u16><<<dim3(1, 1, 512), dim3(256), 0, stream>>>(vT, kdT, Ubuf,
      128, 128, 128, 2048, 2048, 128, 0,
      16, 262144L, 128L, 262144L, 128L, 262144L, 16384L, nullptr, nullptr, nullptr);
  scan_state<<<dim3(256), dim3(256), 0, stream>>>(Ubuf, S_all);
  attn_out<<<dim3(512), dim3(256), 0, stream>>>(qkvg, vT, S_all, wg2t, nw, nrm);
  // 4. output projection
  gemm_bt<float><<<dim3(16, 32, 1), dim3(256), 0, stream>>>(nrm, wot, out,
      4096, 2048, 2048, 2048, 2048, 2048, 0, 1, 0, 0, 0, 0, 0, 0, nullptr, nullptr, nullptr);
}

// Round 10
// 379.381 us; speedup vs baseline: 1.1064x; 1.0019x over previous
//
#include <hip/hip_runtime.h>

// LinearAttention forward on gfx950.
// R4:  Wg1 folded into QKV GEMM; silu+rotate fused into QKV epilogue via
//      permuted q/k weight columns; gated RMSNorm fused into attn_out.
// R8:  sigmoid fused into gate GEMM; factored score-decay exp; attn_out 2/CU.
// R10: rope LUT; v stored transposed into vT from QKV epilogue; merged prep.
// R12: register-cliff fix: gemm_bt launch_bounds(256,4); sV overlays sA/sB.
// R13: k-transpose+decay fused into QKV epilogue; gate GEMM fused into
//      attn_out phase 4. 6 dispatches. (380.1 us)
// R14: k-epilogue dedup — silu+rotate applied IN PLACE into acc during the
//      row-store pass; the two kdT half-passes now only scale by the decay
//      chain (removes 128 expf + 64 rope reloads per k-block thread).

#define DEV __device__ __forceinline__
typedef unsigned short u16;
typedef __bf16 bf16x8 __attribute__((ext_vector_type(8)));
typedef float f32x4 __attribute__((ext_vector_type(4)));
typedef u16 u16x8 __attribute__((ext_vector_type(8)));
typedef u16 u16x4 __attribute__((ext_vector_type(4)));

DEV u16 f2bf(float f) {
  unsigned u = __builtin_bit_cast(unsigned, f);
  u += 0x7fffu + ((u >> 16) & 1u);
  return (u16)(u >> 16);
}
DEV float bf2f(u16 h) {
  unsigned u = ((unsigned)h) << 16;
  return __builtin_bit_cast(float, u);
}
DEV void async16(const u16* g, u16* l) {
  __builtin_amdgcn_global_load_lds(
      (const __attribute__((address_space(1))) unsigned int*)g,
      (__attribute__((address_space(3))) unsigned int*)l, 16, 0, 0);
}

// ---------------- prep: x->bf16 | weight transposes | rope LUT ----------------
__global__ void prep_all(const float* __restrict__ x,
                         const float* __restrict__ Wq, const float* __restrict__ Wk,
                         const float* __restrict__ Wv, const float* __restrict__ Wo,
                         const float* __restrict__ Wg1, const float* __restrict__ Wg2,
                         u16* __restrict__ xb, u16* __restrict__ wtqkvg,
                         u16* __restrict__ wot, u16* __restrict__ wg2t,
                         float* __restrict__ rope) {
  int id = blockIdx.x;
  if (id < 8192) {
    long i = ((long)id * 256 + threadIdx.x) * 4;
    float4 v = *(const float4*)(x + i);
    ushort4 p;
    p.x = f2bf(v.x); p.y = f2bf(v.y); p.z = f2bf(v.z); p.w = f2bf(v.w);
    *(ushort4*)(xb + i) = p;
    return;
  }
  if (id >= 25088) {
    int idx = (id - 25088) * 256 + threadIdx.x;  // 131072 = 2048 t x 64 jj
    int t = idx >> 6, jj = idx & 63;
    float th = exp2f(-13.287712379549449f * (float)jj * (1.f / 64.f));
    float sn, cs;
    sincosf((float)t * th, &sn, &cs);
    ((float2*)rope)[idx] = make_float2(cs, sn);
    return;
  }
  id -= 8192;
  __shared__ float t[32][33];
  const float* in; u16* out; int K, N, bx, by;
  bool perm = false;
  if (id < 12288) {
    int w = id >> 12, tt = id & 4095;
    in = (w == 0) ? Wq : (w == 1) ? Wk : Wv;
    out = wtqkvg + (long)w * 2048 * 2048;
    K = 2048; N = 2048; bx = tt & 63; by = tt >> 6;
    perm = (w < 2);
  } else if (id < 16384) {
    int tt = id - 12288;
    in = Wo; out = wot; K = 2048; N = 2048; bx = tt & 63; by = tt >> 6;
  } else if (id < 16640) {
    int tt = id - 16384;
    in = Wg1; out = wtqkvg + 6144L * 2048; K = 2048; N = 128; bx = tt & 3; by = tt >> 2;
  } else {
    int tt = id - 16640;
    in = Wg2; out = wg2t; K = 128; N = 2048; bx = tt & 63; by = tt >> 6;
  }
  int c = threadIdx.x & 31, r0 = threadIdx.x >> 5;
  for (int r = r0; r < 32; r += 8)
    t[r][c] = in[(long)(by * 32 + r) * N + bx * 32 + c];
  __syncthreads();
  for (int r = r0; r < 32; r += 8) {
    int n = bx * 32 + r, nr = n;
    if (perm) {
      int h = n >> 7, j = n & 127, jj = j & 63, hi = j >> 6;
      nr = h * 128 + (jj & 15) + 32 * (jj >> 4) + 16 * hi;
    }
    out[(long)nr * K + by * 32 + c] = f2bf(t[c][r]);
  }
}

// ---------------- GEMM: C[M][N] = A[M][K] @ B^T, B stored [N][K], bf16 in ----------------
// rot=1: cols<2048 q: silu+rotate rows. cols [2048,4096) k: silu+rotate rows
//        (in-place into acc) AND decayed transpose into KT (sV overlay,
//        2 half-passes, scale-only). cols [4096,6144) v: transpose into VT.
template <typename OutT>
__global__ __launch_bounds__(256, 4) void gemm_bt(
    const u16* __restrict__ A, const u16* __restrict__ B, OutT* __restrict__ C,
    int M, int N, int K, int lda, int ldb, int ldc, int rot,
    int nc, long sA1, long sA2, long sB1, long sB2, long sC1, long sC2,
    const float* __restrict__ rope, u16* __restrict__ VT, u16* __restrict__ KT) {
  __shared__ u16 smem[8192];  // sA[0:4096] | sB[4096:8192]; reused as sV[64][128]
  u16* const sA = smem;
  u16* const sB = smem + 4096;
  {
    int z = blockIdx.z, z1 = z / nc, z2 = z % nc;
    A += z1 * sA1 + z2 * sA2;
    B += z1 * sB1 + z2 * sB2;
    C += z1 * sC1 + z2 * sC2;
  }
  int bxs, bys;
  {
    int lin = blockIdx.x + gridDim.x * blockIdx.y;
    int per = 16 * gridDim.y;
    int g = lin / per, r = lin % per;
    int base = g * 16;
    int w = min(16, (int)gridDim.x - base);
    bxs = base + r % w; bys = r / w;
  }
  const int tid = threadIdx.x, lane = tid & 63, wid = tid >> 6;
  const int bm = bys * 128, bn = bxs * 128;
  const int ch0 = wid * 2, ch1 = ch0 + 1;
  const int lr = lane >> 2;                                  // local row 0..15
  const int ak = (((lane & 3) - ((lane >> 3) & 3)) & 3) * 8; // rotated k-piece
  const int ar0 = ch0 * 16 + lr, ar1 = ch1 * 16 + lr;
  const u16* gA0 = A + (long)(bm + ar0) * lda + ak;
  const u16* gA1 = A + (long)(bm + ar1) * lda + ak;
  const u16* gB0 = B + (long)(bn + ar0) * ldb + ak;
  const u16* gB1 = B + (long)(bn + ar1) * ldb + ak;
  u16* lA0 = sA + ch0 * 512; u16* lA1 = sA + ch1 * 512;
  u16* lB0 = sB + ch0 * 512; u16* lB1 = sB + ch1 * 512;
  const int wm = (wid & 1) * 64, wn = (wid >> 1) * 64;
  const int fm = lane & 15, kq = lane >> 4;
  const int qs = ((kq + (fm >> 1)) & 3) * 8;
  const int aoff = (wm >> 4) * 512 + fm * 32 + qs;
  const int boff = (wn >> 4) * 512 + fm * 32 + qs;
  f32x4 acc[4][4] = {};
  for (int kb = 0; kb < K; kb += 32) {
    async16(gA0, lA0); async16(gA1, lA1);
    async16(gB0, lB0); async16(gB1, lB1);
    gA0 += 32; gA1 += 32; gB0 += 32; gB1 += 32;
    __syncthreads();
    bf16x8 af[4], bfr[4];
#pragma unroll
    for (int i = 0; i < 4; i++) af[i] = *(const bf16x8*)&sA[aoff + i * 512];
#pragma unroll
    for (int i = 0; i < 4; i++) bfr[i] = *(const bf16x8*)&sB[boff + i * 512];
#pragma unroll
    for (int mt = 0; mt < 4; mt++)
#pragma unroll
      for (int nt = 0; nt < 4; nt++)
        acc[mt][nt] = __builtin_amdgcn_mfma_f32_16x16x32_bf16(af[mt], bfr[nt], acc[mt][nt], 0, 0, 0);
    __syncthreads();
  }
  const int cr = (lane >> 4) * 4;
  if constexpr (sizeof(OutT) == 2) {
    if (rot == 1 && bn < 4096) {
      // silu + rotate IN PLACE into acc, then row-store.
#pragma unroll
      for (int mt = 0; mt < 4; mt++)
#pragma unroll
        for (int r = 0; r < 4; r++) {
          long row = bm + wm + mt * 16 + cr + r;
          const float2* rp = (const float2*)rope + (long)(row & 2047) * 64;
#pragma unroll
          for (int np = 0; np < 4; np += 2) {
            float x1 = acc[mt][np][r], x2 = acc[mt][np + 1][r];
            x1 = x1 / (1.f + __expf(-x1));
            x2 = x2 / (1.f + __expf(-x2));
            int jj = fm + 16 * ((wn >> 5) + (np >> 1));
            float2 cn = rp[jj];
            float y0 = x1 * cn.x - x2 * cn.y;
            float y1 = x1 * cn.y + x2 * cn.x;
            acc[mt][np][r] = y0;
            acc[mt][np + 1][r] = y1;
            C[row * ldc + bn + jj]      = f2bf(y0);
            C[row * ldc + bn + 64 + jj] = f2bf(y1);
          }
        }
      if (bn >= 2048) {
        // k: decayed transpose KT[(b*16+h)*128+d][n]; acc already rotated.
        const int head = (bn - 2048) >> 7;
        const int bq = bm >> 11, tb = bm & 2047;
        const float llk = -exp2f(-0.5f * (float)(head + 1));
        const float em = __expf(-llk);
        u16* kt = KT + (long)(bq * 16 + head) * 128 * 2048 + tb;
        u16* const sV = smem;
#pragma unroll
        for (int half = 0; half < 2; half++) {
          __syncthreads();
#pragma unroll
          for (int mt = 0; mt < 4; mt++) {
            int t0 = wm + mt * 16 + cr;
            float d0 = __expf(llk * (float)(127 - t0));
#pragma unroll
            for (int np = 0; np < 4; np += 2) {
              int jj = fm + 16 * ((wn >> 5) + (np >> 1));
              u16x4 pk;
              float dd = d0;
#pragma unroll
              for (int r = 0; r < 4; r++) {
                float y = half ? acc[mt][np + 1][r] : acc[mt][np][r];
                pk[r] = f2bf(y * dd);
                dd *= em;
              }
              *(u16x4*)&sV[jj * 128 + (t0 ^ ((jj & 15) << 3))] = pk;
            }
          }
          __syncthreads();
#pragma unroll
          for (int it = 0; it < 4; it++) {
            int dl = it * 16 + (tid >> 4);
            int tc = (tid & 15) * 8;
            u16x8 vv = *(const u16x8*)&sV[dl * 128 + (tc ^ ((dl & 15) << 3))];
            *(u16x8*)(kt + (long)(half * 64 + dl) * 2048 + tc) = vv;
          }
        }
      }
      return;
    }
    if (rot == 1 && bn < 6144) {
      // v block: 128t x 128d of one (b,h). Transpose via sV (= smem overlay,
      // XOR-swizzled [64][128]) per d-half; stores 16B-contig into vT.
      const int bq = bm >> 11;
      const int head = (bn - 4096) >> 7;
      const int tb = bm & 2047;
      u16* vbase = VT + (long)(bq * 16 + head) * 128 * 2048 + tb;
      u16* const sV = smem;
#pragma unroll
      for (int dh = 0; dh < 2; dh++) {
        __syncthreads();
        if ((wid >> 1) == dh) {
#pragma unroll
          for (int mt = 0; mt < 4; mt++)
#pragma unroll
            for (int nt = 0; nt < 4; nt++) {
              int dl = nt * 16 + fm;
              int t0 = wm + mt * 16 + cr;
              u16x4 pk;
#pragma unroll
              for (int r = 0; r < 4; r++) pk[r] = f2bf(acc[mt][nt][r]);
              *(u16x4*)&sV[dl * 128 + (t0 ^ ((fm & 15) << 3))] = pk;
            }
        }
        __syncthreads();
#pragma unroll
        for (int it = 0; it < 4; it++) {
          int dl = it * 16 + (tid >> 4);
          int tc = (tid & 15) * 8;
          u16x8 vv = *(const u16x8*)&sV[dl * 128 + (tc ^ ((dl & 15) << 3))];
          *(u16x8*)(vbase + (long)(dh * 64 + dl) * 2048 + tc) = vv;
        }
      }
      return;
    }
  }
#pragma unroll
  for (int mt = 0; mt < 4; mt++)
#pragma unroll
    for (int nt = 0; nt < 4; nt++)
#pragma unroll
      for (int r = 0; r < 4; r++) {
        long row = bm + wm + mt * 16 + cr + r;
        long col = bn + wn + nt * 16 + fm;
        float v = acc[mt][nt][r];
        if constexpr (sizeof(OutT) == 2) C[row * ldc + col] = f2bf(v);
        else                             C[row * ldc + col] = v;
      }
}

// ---------------- decay scan over chunks: S_c = lamC*S_{c-1} + U_{c-1}, S_0 = 0 ----------------
__global__ void scan_state(const u16* __restrict__ U, u16* __restrict__ S_all) {
  int blk = blockIdx.x; // 256 blocks: [bh:32][slice:8]
  int bh = blk >> 3, sl = blk & 7, h = bh & 15;
  float log_lam = -exp2f(-0.5f * (float)(h + 1));
  float lamC = expf(log_lam * 128.f);
  long off = (long)bh * 16 * 16384 + sl * 2048 + threadIdx.x * 8;
  float s[8];
#pragma unroll
  for (int j = 0; j < 8; j++) s[j] = 0.f;
  for (int c = 0; c < 16; c++) {
    long idx = off + (long)c * 16384;
    u16x8 sb;
#pragma unroll
    for (int j = 0; j < 8; j++) sb[j] = f2bf(s[j]);
    *(u16x8*)(S_all + idx) = sb;
    u16x8 ub = *(const u16x8*)(U + idx);
#pragma unroll
    for (int j = 0; j < 8; j++) s[j] = lamC * s[j] + bf2f(ub[j]);
  }
}

// ---------------- fused per-(b,h,c) attention output + gate GEMM + gated RMSNorm ----------------
__global__ __launch_bounds__(256, 2) void attn_out(
    const u16* __restrict__ qkv, const u16* __restrict__ vT,
    const u16* __restrict__ S_all, const u16* __restrict__ wg2t,
    const float* __restrict__ nw, u16* __restrict__ nrm) {
  __shared__ u16 sA[128 * 32], sB[128 * 32], sK[128 * 32];
  __shared__ u16 sS[128 * 136]; // stride 136: breaks 16-way bank conflict
  __shared__ float sNorm[2][128];
  const int blk = blockIdx.x;
  const int bh = blk >> 4, c = blk & 15;
  const int b = bh >> 4, h = bh & 15;
  const float log_lam = -exp2f(-0.5f * (float)(h + 1));
  const int tid = threadIdx.x, lane = tid & 63, wid = tid >> 6;
  const int wm = (wid & 1) * 64, wn = (wid >> 1) * 64;
  const int fm = lane & 15, fq = lane >> 4, kq = lane >> 4;
  const int lr = lane >> 2;
  const int ak = (((lane & 3) - ((lane >> 3) & 3)) & 3) * 8;
  const int ch0 = wid * 2, ch1 = ch0 + 1;
  const int r0 = ch0 * 16 + lr, r1 = ch1 * 16 + lr;
  const int qs = ((kq + (fm >> 1)) & 3) * 8;
  const int aoff = (wm >> 4) * 512 + fm * 32 + qs;
  const int boff = (wn >> 4) * 512 + fm * 32 + qs;
  const u16* qbase = qkv + (long)(b * 2048 + c * 128) * 6272 + h * 128; // rows t, stride 6272
  const u16* kbase = qbase + 2048;                                     // rows s
  const u16* g1base = qkv + (long)(b * 2048 + c * 128) * 6272 + 6144;  // rows t, K=128
  const u16* Sbase = S_all + ((long)bh * 16 + c) * 16384;              // [e][d], stride 128
  const u16* vbase = vT + (long)bh * 262144 + (long)c * 128;           // rows e, stride 2048
  const u16* wbase = wg2t + (long)(h * 128) * 128;                     // rows e, K=128

  f32x4 acc[4][4] = {}; // o_inter, then O total
  f32x4 sc[4][4] = {};  // scores
  // Phase 1+2: o_inter = Q @ S_c   and   scores = Q @ K^T (shared Q staging)
  for (int kb = 0; kb < 128; kb += 32) {
    async16(qbase + (long)r0 * 6272 + kb + ak, sA + ch0 * 512);
    async16(qbase + (long)r1 * 6272 + kb + ak, sA + ch1 * 512);
    async16(Sbase + r0 * 128 + kb + ak, sB + ch0 * 512);
    async16(Sbase + r1 * 128 + kb + ak, sB + ch1 * 512);
    async16(kbase + (long)r0 * 6272 + kb + ak, sK + ch0 * 512);
    async16(kbase + (long)r1 * 6272 + kb + ak, sK + ch1 * 512);
    __syncthreads();
    bf16x8 aq[4], bs[4], bk[4];
#pragma unroll
    for (int i = 0; i < 4; i++) {
      aq[i] = *(const bf16x8*)&sA[aoff + i * 512];
      bs[i] = *(const bf16x8*)&sB[boff + i * 512];
      bk[i] = *(const bf16x8*)&sK[boff + i * 512];
    }
#pragma unroll
    for (int mt = 0; mt < 4; mt++)
#pragma unroll
      for (int nt = 0; nt < 4; nt++) {
        acc[mt][nt] = __builtin_amdgcn_mfma_f32_16x16x32_bf16(aq[mt], bs[nt], acc[mt][nt], 0, 0, 0);
        sc[mt][nt] = __builtin_amdgcn_mfma_f32_16x16x32_bf16(aq[mt], bk[nt], sc[mt][nt], 0, 0, 0);
      }
    __syncthreads();
  }
  // scale o_inter rows by decay_q(t) = exp(log_lam*(t+1))
#pragma unroll
  for (int mt = 0; mt < 4; mt++)
#pragma unroll
    for (int r = 0; r < 4; r++) {
      int t = wm + mt * 16 + fq * 4 + r;
      float d = __expf(log_lam * (float)(t + 1));
#pragma unroll
      for (int nt = 0; nt < 4; nt++) acc[mt][nt][r] *= d;
    }
  // mask+decay scores, write bf16 to sS[t][s] (factored exp; masked lanes'
  // possible inf discarded by the select).
  float eS[4];
#pragma unroll
  for (int nt = 0; nt < 4; nt++)
    eS[nt] = __expf(log_lam * (float)(63 - (nt * 16 + fm)));
#pragma unroll
  for (int mt = 0; mt < 4; mt++)
#pragma unroll
    for (int r = 0; r < 4; r++) {
      int t = wm + mt * 16 + fq * 4 + r;
      float eT = __expf(log_lam * (float)(t - wn - 63));
#pragma unroll
      for (int nt = 0; nt < 4; nt++) {
        int s = wn + nt * 16 + fm;
        float v = sc[mt][nt][r];
        v = (t >= s) ? v * (eT * eS[nt]) : 0.f;
        sS[t * 136 + s] = f2bf(v);
      }
    }
  __syncthreads();
  // Phase 3: O += scores @ V   (A from sS, B staged from vT)
  for (int kb = 0; kb < 128; kb += 32) {
    async16(vbase + r0 * 2048 + kb + ak, sB + ch0 * 512);
    async16(vbase + r1 * 2048 + kb + ak, sB + ch1 * 512);
    __syncthreads();
    bf16x8 as[4], bv[4];
#pragma unroll
    for (int i = 0; i < 4; i++) {
      as[i] = *(const bf16x8*)&sS[(wm + i * 16 + fm) * 136 + kb + kq * 8];
      bv[i] = *(const bf16x8*)&sB[boff + i * 512];
    }
#pragma unroll
    for (int mt = 0; mt < 4; mt++)
#pragma unroll
      for (int nt = 0; nt < 4; nt++)
        acc[mt][nt] = __builtin_amdgcn_mfma_f32_16x16x32_bf16(as[mt], bv[nt], acc[mt][nt], 0, 0, 0);
    __syncthreads();
  }
  // Phase 4: gate = g1 @ Wg2t^T (head h cols); gsc reuses dead sc registers.
  f32x4 gsc[4][4] = {};
  for (int kb = 0; kb < 128; kb += 32) {
    async16(g1base + (long)r0 * 6272 + kb + ak, sA + ch0 * 512);
    async16(g1base + (long)r1 * 6272 + kb + ak, sA + ch1 * 512);
    async16(wbase + r0 * 128 + kb + ak, sB + ch0 * 512);
    async16(wbase + r1 * 128 + kb + ak, sB + ch1 * 512);
    __syncthreads();
    bf16x8 ag[4], bw[4];
#pragma unroll
    for (int i = 0; i < 4; i++) {
      ag[i] = *(const bf16x8*)&sA[aoff + i * 512];
      bw[i] = *(const bf16x8*)&sB[boff + i * 512];
    }
#pragma unroll
    for (int mt = 0; mt < 4; mt++)
#pragma unroll
      for (int nt = 0; nt < 4; nt++)
        gsc[mt][nt] = __builtin_amdgcn_mfma_f32_16x16x32_bf16(ag[mt], bw[nt], gsc[mt][nt], 0, 0, 0);
    __syncthreads();
  }
  // ---- fused gated group-RMSNorm: x = O*sigmoid(gate) ----
  float nwv[4];
#pragma unroll
  for (int nt = 0; nt < 4; nt++) nwv[nt] = nw[h * 128 + wn + nt * 16 + fm];
  float part[4][4];
#pragma unroll
  for (int mt = 0; mt < 4; mt++)
#pragma unroll
    for (int r = 0; r < 4; r++) {
      float p = 0.f;
#pragma unroll
      for (int nt = 0; nt < 4; nt++) {
        float g = 1.f / (1.f + __expf(-gsc[mt][nt][r]));
        float x = acc[mt][nt][r] * g;
        acc[mt][nt][r] = x;
        p += x * x;
      }
      part[mt][r] = p;
    }
#pragma unroll
  for (int o = 1; o < 16; o <<= 1)
#pragma unroll
    for (int mt = 0; mt < 4; mt++)
#pragma unroll
      for (int r = 0; r < 4; r++) part[mt][r] += __shfl_xor(part[mt][r], o);
  if (fm == 0) {
#pragma unroll
    for (int mt = 0; mt < 4; mt++)
#pragma unroll
      for (int r = 0; r < 4; r++)
        sNorm[wid >> 1][wm + mt * 16 + fq * 4 + r] = part[mt][r];
  }
  __syncthreads();
  long orow0 = (long)(b * 2048 + c * 128);
#pragma unroll
  for (int mt = 0; mt < 4; mt++)
#pragma unroll
    for (int r = 0; r < 4; r++) {
      int t = wm + mt * 16 + fq * 4 + r;
      float ms = (sNorm[0][t] + sNorm[1][t]) * (1.f / 128.f);
      float rs = rsqrtf(ms + 1e-6f);
#pragma unroll
      for (int nt = 0; nt < 4; nt++) {
        int e = wn + nt * 16 + fm;
        nrm[(orow0 + t) * 2048 + h * 128 + e] = f2bf(acc[mt][nt][r] * rs * nwv[nt]);
      }
    }
}

// ---------------- host ----------------
extern "C" void kernel_launch(void* const* d_in, const int* in_sizes, int n_in,
                              void* d_out, int out_size, void* d_ws, size_t ws_size,
                              hipStream_t stream) {
  (void)in_sizes; (void)n_in; (void)out_size; (void)ws_size;
  const float* x   = (const float*)d_in[0];
  const float* Wq  = (const float*)d_in[1];
  const float* Wk  = (const float*)d_in[2];
  const float* Wv  = (const float*)d_in[3];
  const float* Wo  = (const float*)d_in[4];
  const float* Wg1 = (const float*)d_in[5];
  const float* Wg2 = (const float*)d_in[6];
  const float* nw  = (const float*)d_in[7];
  float* out = (float*)d_out;

  char* ws = (char*)d_ws;
  size_t off = 0;
  auto alloc = [&](size_t bytes) -> void* {
    void* p = ws + off;
    off += (bytes + 255) & ~(size_t)255;
    return p;
  };
  u16* xb    = (u16*)alloc(4096UL * 2048 * 2);
  u16* wtqkv = (u16*)alloc(6272UL * 2048 * 2); // [Wq^T perm | Wk^T perm | Wv^T | Wg1^T]
  u16* wot   = (u16*)alloc(2048UL * 2048 * 2);
  u16* wg2t  = (u16*)alloc(2048UL * 128 * 2);
  u16* qkvg  = (u16*)alloc(4096UL * 6272 * 2); // q(rot) | k(rot) | (v slot unused) | g1
  u16* kdT   = (u16*)alloc(32UL * 128 * 2048 * 2);
  u16* vT    = (u16*)alloc(32UL * 128 * 2048 * 2);
  u16* Ubuf  = (u16*)alloc(512UL * 16384 * 2);
  u16* S_all = (u16*)alloc(512UL * 16384 * 2);
  u16* nrm   = (u16*)alloc(4096UL * 2048 * 2);
  float* rope = (float*)alloc(2048UL * 64 * 8); // float2 [t][jj]

  // 1. prep: x conversion, weight transposes, rope LUT (one launch)
  prep_all<<<dim3(25600), dim3(256), 0, stream>>>(x, Wq, Wk, Wv, Wo, Wg1, Wg2,
                                                  xb, wtqkv, wot, wg2t, rope);
  // 2. QKV+g1 projection: silu+rotate on q,k; k also -> kdT (decayed); v -> vT
  gemm_bt<u16><<<dim3(49, 32, 1), dim3(256), 0, stream>>>(xb, wtqkv, qkvg,
      4096, 6272, 2048, 2048, 2048, 6272, 1, 1, 0, 0, 0, 0, 0, 0, rope, vT, kdT);
  // 3. attention: U per chunk, scan, fused output+gate+RMSNorm
  gemm_bt<u16><<<dim3(1, 1, 512), dim3(256), 0, stream>>>(vT, kdT, Ubuf,
      128, 128, 128, 2048, 2048, 128, 0,
      16, 262144L, 128L, 262144L, 128L, 262144L, 16384L, nullptr, nullptr, nullptr);
  scan_state<<<dim3(256), dim3(256), 0, stream>>>(Ubuf, S_all);
  attn_out<<<dim3(512), dim3(256), 0, stream>>>(qkvg, vT, S_all, wg2t, nw, nrm);
  // 4. output projection
  gemm_bt<float><<<dim3(16, 32, 1), dim3(256), 0, stream>>>(nrm, wot, out,
      4096, 2048, 2048, 2048, 2048, 2048, 0, 1, 0, 0, 0, 0, 0, 0, nullptr, nullptr, nullptr);
}